// Round 14
// baseline (1510.268 us; speedup 1.0000x reference)
//
#include <hip/hip_runtime.h>
#include <math.h>

typedef float f32x4 __attribute__((ext_vector_type(4)));
typedef __bf16 bf16x8 __attribute__((ext_vector_type(8)));
typedef unsigned short u16x8 __attribute__((ext_vector_type(8)));

static constexpr int Dm  = 2048;
static constexpr int Tm  = 2048;
static constexpr int Hm  = 16;
static constexpr int KVm = 8;
static constexpr int HDm = 128;
static constexpr int FFm = 6144;
static constexpr int Vm  = 32000;
static constexpr int QKVN = 4096;

__device__ __forceinline__ float b2f(unsigned short u) {
  unsigned int x = ((unsigned int)u) << 16;
  return __builtin_bit_cast(float, x);
}
__device__ __forceinline__ unsigned short f2b(float f) {
  return __builtin_bit_cast(unsigned short, (__bf16)f);   // v_cvt RTNE
}
__device__ __forceinline__ f32x4 mfma16x16x32(bf16x8 a, bf16x8 b, f32x4 c) {
  return __builtin_amdgcn_mfma_f32_16x16x32_bf16(a, b, c, 0, 0, 0);
}

// async global->LDS, 16B/lane; LDS dest = wave-uniform base + lane*16
__device__ __forceinline__ void gload16(const void* g, void* lds) {
  __builtin_amdgcn_global_load_lds(
      (const __attribute__((address_space(1))) unsigned int*)g,
      (__attribute__((address_space(3))) unsigned int*)lds, 16, 0, 0);
}

// bijective chunked XCD swizzle (m204)
__device__ __forceinline__ int xcd_swz(int o, int nwg) {
  int q = nwg >> 3, r8 = nwg & 7;
  int xcd = o & 7, pos = o >> 3;
  return (xcd < r8) ? xcd * (q + 1) + pos : r8 * (q + 1) + (xcd - r8) * q + pos;
}

// ---------------------------------------------------------------------------
__global__ void rope_tables_k(float* __restrict__ cosT, float* __restrict__ sinT) {
  int t = blockIdx.x;
  int i = threadIdx.x;      // 0..63
  double inv = pow(1000000.0, -(double)i / 64.0);
  double ang = (double)t * inv;
  cosT[t * 64 + i] = (float)cos(ang);
  sinT[t * 64 + i] = (float)sin(ang);
}

__global__ __launch_bounds__(256) void embed_k(const int* __restrict__ ids,
                                               const float* __restrict__ emb,
                                               float* __restrict__ x) {
  int t = blockIdx.x;
  int d0 = threadIdx.x * 8;
  int id = ids[t];
  const float* src = emb + (size_t)id * Dm + d0;
  float* dst = x + (size_t)t * Dm + d0;
  *(f32x4*)dst       = *(const f32x4*)src;
  *(f32x4*)(dst + 4) = *(const f32x4*)(src + 4);
}

// fp32 -> bf16 flat convert, 2048 elems per block
__global__ __launch_bounds__(256) void cvt_flat_k(const float* __restrict__ src,
                                                  unsigned short* __restrict__ dst) {
  size_t i = ((size_t)blockIdx.x * 256 + threadIdx.x) * 8;
  f32x4 a = *(const f32x4*)(src + i);
  f32x4 b = *(const f32x4*)(src + i + 4);
  u16x8 o;
  o[0] = f2b(a.x); o[1] = f2b(a.y); o[2] = f2b(a.z); o[3] = f2b(a.w);
  o[4] = f2b(b.x); o[5] = f2b(b.y); o[6] = f2b(b.z); o[7] = f2b(b.w);
  *(u16x8*)(dst + i) = o;
}

__global__ __launch_bounds__(256) void rmsnorm_k(const float* __restrict__ x,
                                                 const float* __restrict__ g,
                                                 unsigned short* __restrict__ y) {
  int t = blockIdx.x;
  const float* xr = x + (size_t)t * Dm;
  float vals[8];
  float s = 0.f;
#pragma unroll
  for (int i = 0; i < 8; ++i) {
    float vv = xr[threadIdx.x + i * 256];
    vals[i] = vv;
    s += vv * vv;
  }
#pragma unroll
  for (int off = 32; off; off >>= 1) s += __shfl_xor(s, off);
  __shared__ float red[4];
  if ((threadIdx.x & 63) == 0) red[threadIdx.x >> 6] = s;
  __syncthreads();
  s = (red[0] + red[1]) + (red[2] + red[3]);
  float r = rsqrtf(s * (1.f / Dm) + 1e-6f);
  unsigned short* yr = y + (size_t)t * Dm;
#pragma unroll
  for (int i = 0; i < 8; ++i) {
    int d = threadIdx.x + i * 256;
    yr[d] = f2b(vals[i] * r * g[d]);
  }
}

__global__ __launch_bounds__(256) void qknorm_rope_k(unsigned short* __restrict__ q,
                                                     const float* __restrict__ nrm,
                                                     const float* __restrict__ cosT,
                                                     const float* __restrict__ sinT,
                                                     int nheads) {
  int gw = (int)((blockIdx.x * blockDim.x + threadIdx.x) >> 6);
  int lane = threadIdx.x & 63;
  int t = gw / nheads, h = gw % nheads;
  unsigned short* row = q + ((size_t)t * nheads + h) * HDm;
  float x1 = b2f(row[lane]);
  float x2 = b2f(row[lane + 64]);
  float s = x1 * x1 + x2 * x2;
#pragma unroll
  for (int off = 32; off; off >>= 1) s += __shfl_xor(s, off);
  float r = rsqrtf(s * (1.f / HDm) + 1e-6f);
  float y1 = x1 * r * nrm[lane];
  float y2 = x2 * r * nrm[lane + 64];
  float c = cosT[t * 64 + lane];
  float sn = sinT[t * 64 + lane];
  row[lane]      = f2b(y1 * c - y2 * sn);
  row[lane + 64] = f2b(y2 * c + y1 * sn);
}

// Weight convert+transpose: W fp32 [K][N] -> Wt bf16 [N][K]
__global__ __launch_bounds__(256) void cvtT_k(const float* __restrict__ W,
                                              unsigned short* __restrict__ Wt,
                                              int K, int N) {
  __shared__ __align__(16) unsigned short tile[64][68];
  const int n0 = blockIdx.x * 64, k0 = blockIdx.y * 64;
  const int tid = threadIdx.x;
#pragma unroll
  for (int i = 0; i < 4; ++i) {
    int e = tid + i * 256;
    int r = e >> 4, c4 = (e & 15) * 4;
    f32x4 v = *(const f32x4*)(W + (size_t)(k0 + r) * N + n0 + c4);
    tile[r][c4 + 0] = f2b(v.x);
    tile[r][c4 + 1] = f2b(v.y);
    tile[r][c4 + 2] = f2b(v.z);
    tile[r][c4 + 3] = f2b(v.w);
  }
  __syncthreads();
#pragma unroll
  for (int i = 0; i < 2; ++i) {
    int e = tid + i * 256;
    int rr = e >> 3, cc = (e & 7) * 8;
    u16x8 o;
#pragma unroll
    for (int j = 0; j < 8; ++j) o[j] = tile[cc + j][rr];
    *(u16x8*)(Wt + (size_t)(n0 + rr) * K + k0 + cc) = o;
  }
}

// ---------------------------------------------------------------------------
// 2-phase 128^2 GEMM (round-12 proven) + split-K support (r14):
// row stride ld (>= K); blockIdx.z selects K-chunk [z*K, z*K+K).
// EPI=1: f32 += (single chunk only). EPI=4: f32 atomicAdd (split-K safe).
template <int EPI, bool OUTF32>
__global__ __launch_bounds__(256) void gemm2p_k(const unsigned short* __restrict__ A,
                                                const unsigned short* __restrict__ B,
                                                void* __restrict__ C,
                                                void* __restrict__ C2,
                                                void* __restrict__ C3,
                                                int N, int K, int ld, int cOff) {
  __shared__ __align__(16) unsigned short lds[2][2][128 * 64];   // 64 KiB
  const int tid = threadIdx.x;
  const int nwg = gridDim.x * gridDim.y;
  const int nid = xcd_swz(blockIdx.x + gridDim.x * blockIdx.y, nwg);
  const int bm = nid % gridDim.x, bn = nid / gridDim.x;
  const int w = tid >> 6, lane = tid & 63;
  const int wm = (w >> 1) * 64, wn = (w & 1) * 64;
  const int lr = lane & 15, hi = lane >> 4;
  const int rowA0 = bm * 128, colB0 = bn * 128;
  const int nk = K >> 6;
  const int kz = blockIdx.z * K;         // split-K chunk offset

  const int srow = lane >> 3;            // row within 8-row chunk
  const int ulog = (lane & 7) ^ srow;    // pre-swizzled logical k-unit
  const unsigned short* gA = A + (size_t)(rowA0 + w * 32 + srow) * ld + kz + ulog * 8;
  const unsigned short* gB = B + (size_t)(colB0 + w * 32 + srow) * ld + kz + ulog * 8;

  int uu[2];
  uu[0] = ((0 + hi) ^ (lr & 7)) * 8;
  uu[1] = ((4 + hi) ^ (lr & 7)) * 8;

  f32x4 acc[4][4] = {};

  auto stage8 = [&](int buf, int k0) {
    unsigned short* lA = &lds[buf][0][(w * 32) * 64];
    unsigned short* lB = &lds[buf][1][(w * 32) * 64];
#pragma unroll
    for (int i = 0; i < 4; ++i) {
      gload16(gA + (size_t)(i * 8) * ld + k0, lA + i * 8 * 64);
      gload16(gB + (size_t)(i * 8) * ld + k0, lB + i * 8 * 64);
    }
  };

  stage8(0, 0);
  asm volatile("s_waitcnt vmcnt(0)" ::: "memory");
  __builtin_amdgcn_s_barrier();

  for (int kt = 0; kt < nk; ++kt) {
    const int cur = kt & 1;
    if (kt + 1 < nk) stage8(cur ^ 1, (kt + 1) << 6);   // issue early

    const unsigned short* Ac = &lds[cur][0][0];
    const unsigned short* Bc = &lds[cur][1][0];
    bf16x8 av[4][2], bv[4][2];
#pragma unroll
    for (int m = 0; m < 4; ++m) {
      int rb = (wm + m * 16 + lr) * 64;
#pragma unroll
      for (int ks = 0; ks < 2; ++ks)
        av[m][ks] = *(const bf16x8*)&Ac[rb + uu[ks]];
    }
#pragma unroll
    for (int n = 0; n < 4; ++n) {
      int rb = (wn + n * 16 + lr) * 64;
#pragma unroll
      for (int ks = 0; ks < 2; ++ks)
        bv[n][ks] = *(const bf16x8*)&Bc[rb + uu[ks]];
    }
    __builtin_amdgcn_s_setprio(1);
#pragma unroll
    for (int m = 0; m < 4; ++m)
#pragma unroll
      for (int n = 0; n < 4; ++n)
#pragma unroll
        for (int ks = 0; ks < 2; ++ks)
          acc[m][n] = mfma16x16x32(av[m][ks], bv[n][ks], acc[m][n]);
    __builtin_amdgcn_s_setprio(0);

    asm volatile("s_waitcnt vmcnt(0) lgkmcnt(0)" ::: "memory");
    __builtin_amdgcn_sched_barrier(0);
    __builtin_amdgcn_s_barrier();
  }

  const int r0 = rowA0 + wm + hi * 4;
  const int c0 = wn + lr;
#pragma unroll
  for (int m = 0; m < 4; ++m)
#pragma unroll
    for (int n = 0; n < 4; ++n) {
      const int cc = colB0 + c0 + n * 16;
#pragma unroll
      for (int j = 0; j < 4; ++j) {
        int r = r0 + m * 16 + j;
        if (EPI == 0) {
          size_t idx = (size_t)r * N + cOff + cc;
          if (OUTF32) ((float*)C)[idx] = acc[m][n][j];
          else        ((unsigned short*)C)[idx] = f2b(acc[m][n][j]);
        } else if (EPI == 1) {
          ((float*)C)[(size_t)r * N + cc] += acc[m][n][j];
        } else if (EPI == 2) {
          unsigned short* Cb = (unsigned short*)C;
          size_t idx = (size_t)r * N + cc;
          float gg = b2f(Cb[idx]);
          gg = gg / (1.f + __expf(-gg));
          Cb[idx] = f2b(gg * acc[m][n][j]);
        } else if (EPI == 4) {  // split-K accumulate
          atomicAdd(&((float*)C)[(size_t)r * N + cc], acc[m][n][j]);
        } else {  // EPI==3: QKV split-store
          unsigned short v = f2b(acc[m][n][j]);
          if (cc < 2048)      ((unsigned short*)C )[(size_t)r * 2048 + cc] = v;
          else if (cc < 3072) ((unsigned short*)C2)[(size_t)r * 1024 + (cc - 2048)] = v;
          else                ((unsigned short*)C3)[(size_t)r * 1024 + (cc - 3072)] = v;
        }
      }
    }
}

// ---------------------------------------------------------------------------
// 256^2 8-phase GEMM (round-13 proven, unchanged)
#define LDA256(MH)                                                             \
  _Pragma("unroll") for (int m_ = 0; m_ < 4; ++m_)                             \
  _Pragma("unroll") for (int ks_ = 0; ks_ < 2; ++ks_)                          \
    av[m_][ks_] = *(const bf16x8*)&Ac[aBase + (MH) * 4096 + m_ * 1024 + uu[ks_]];
#define LDB256(NH)                                                             \
  _Pragma("unroll") for (int n_ = 0; n_ < 2; ++n_)                             \
  _Pragma("unroll") for (int ks_ = 0; ks_ < 2; ++ks_)                          \
    bv[n_][ks_] = *(const bf16x8*)&Bc[bBase + (NH) * 2048 + n_ * 1024 + uu[ks_]];
#define MMA256(MH, NH)                                                         \
  __builtin_amdgcn_s_setprio(1);                                               \
  _Pragma("unroll") for (int m_ = 0; m_ < 4; ++m_)                             \
  _Pragma("unroll") for (int n_ = 0; n_ < 2; ++n_)                             \
  _Pragma("unroll") for (int ks_ = 0; ks_ < 2; ++ks_)                          \
    acc[(MH) * 4 + m_][(NH) * 2 + n_] = mfma16x16x32(                          \
        av[m_][ks_], bv[n_][ks_], acc[(MH) * 4 + m_][(NH) * 2 + n_]);          \
  __builtin_amdgcn_s_setprio(0);
#define SYNCV                                                                  \
  asm volatile("s_waitcnt vmcnt(4)" ::: "memory");                             \
  __builtin_amdgcn_s_barrier();                                                \
  asm volatile("s_waitcnt lgkmcnt(0)" ::: "memory");                           \
  __builtin_amdgcn_sched_barrier(0);
#define SYNCNV                                                                 \
  __builtin_amdgcn_s_barrier();                                                \
  asm volatile("s_waitcnt lgkmcnt(0)" ::: "memory");                           \
  __builtin_amdgcn_sched_barrier(0);
#define ENDPH __builtin_amdgcn_s_barrier();

template <int EPI, bool OUTF32>
__global__ __launch_bounds__(512) void gemm256_k(const unsigned short* __restrict__ A,
                                                 const unsigned short* __restrict__ B,
                                                 void* __restrict__ C,
                                                 void* __restrict__ C2,
                                                 void* __restrict__ C3,
                                                 int N, int K, int cOff) {
  __shared__ __align__(16) unsigned short lds[2][2][256 * 64];   // 128 KiB
  const int tid = threadIdx.x;
  const int nwg = gridDim.x * gridDim.y;
  const int nid = xcd_swz(blockIdx.x + gridDim.x * blockIdx.y, nwg);
  const int bm = nid % gridDim.x, bn = nid / gridDim.x;
  const int w = tid >> 6, lane = tid & 63;
  const int wr = w >> 2, wc = w & 3;
  const int lr = lane & 15, hi = lane >> 4;
  const int rowA0 = bm * 256, colB0 = bn * 256;
  const int nk = K >> 6;

  const int srow = lane >> 3;
  const int ulog = (lane & 7) ^ srow;
  const int eaR = (w < 4) ? w * 16 : 128 + (w - 4) * 16;
  const int laR = eaR + 64;
  const int ebR = (w >> 1) * 64 + (w & 1) * 16;
  const int lbR = ebR + 32;
  const unsigned short* gAt = A + (size_t)rowA0 * K + ulog * 8;
  const unsigned short* gBt = B + (size_t)colB0 * K + ulog * 8;

  int uu[2];
  uu[0] = ((0 + hi) ^ (lr & 7)) * 8;
  uu[1] = ((4 + hi) ^ (lr & 7)) * 8;
  const int aBase = (wr * 128 + lr) * 64;
  const int bBase = (wc * 64 + lr) * 64;

  f32x4 acc[8][4] = {};
  bf16x8 av[4][2], bv[2][2];

  auto stage2 = [&](const unsigned short* g, int rbase, unsigned short* l, int k0) {
    gload16(g + (size_t)(rbase + srow) * K + k0, l + rbase * 64);
    gload16(g + (size_t)(rbase + 8 + srow) * K + k0, l + (rbase + 8) * 64);
  };

  stage2(gAt, eaR, &lds[0][0][0], 0);
  stage2(gBt, ebR, &lds[0][1][0], 0);
  stage2(gBt, lbR, &lds[0][1][0], 0);
  stage2(gAt, laR, &lds[0][0][0], 0);
  asm volatile("s_waitcnt vmcnt(0)" ::: "memory");
  __builtin_amdgcn_s_barrier();

  for (int kt = 0; kt < nk; ++kt) {
    unsigned short* Ac = &lds[kt & 1][0][0];
    unsigned short* Bc = &lds[kt & 1][1][0];
    unsigned short* An = &lds[(kt + 1) & 1][0][0];
    unsigned short* Bn = &lds[(kt + 1) & 1][1][0];
    const int k0n = (kt + 1) << 6;
    const bool more = (kt + 1) < nk;

    LDA256(0) LDB256(0)
    if (more) stage2(gAt, eaR, An, k0n);
    SYNCV MMA256(0, 0) ENDPH
    LDB256(1)
    if (more) stage2(gBt, ebR, Bn, k0n);
    SYNCV MMA256(0, 1) ENDPH
    LDA256(1)
    if (more) stage2(gBt, lbR, Bn, k0n);
    SYNCNV MMA256(1, 1) ENDPH
    LDB256(0)
    if (more) stage2(gAt, laR, An, k0n);
    SYNCV MMA256(1, 0) ENDPH
  }

  const int r0 = rowA0 + wr * 128 + hi * 4;
  const int c0 = colB0 + wc * 64 + lr;
#pragma unroll
  for (int mi = 0; mi < 8; ++mi)
#pragma unroll
    for (int n = 0; n < 4; ++n) {
      const int cc = c0 + n * 16;
#pragma unroll
      for (int j = 0; j < 4; ++j) {
        int r = r0 + mi * 16 + j;
        if (EPI == 0) {
          size_t idx = (size_t)r * N + cOff + cc;
          if (OUTF32) ((float*)C)[idx] = acc[mi][n][j];
          else        ((unsigned short*)C)[idx] = f2b(acc[mi][n][j]);
        } else if (EPI == 2) {
          unsigned short* Cb = (unsigned short*)C;
          size_t idx = (size_t)r * N + cc;
          float gg = b2f(Cb[idx]);
          gg = gg / (1.f + __expf(-gg));
          Cb[idx] = f2b(gg * acc[mi][n][j]);
        } else {  // EPI==3: QKV split-store
          unsigned short v = f2b(acc[mi][n][j]);
          if (cc < 2048)      ((unsigned short*)C )[(size_t)r * 2048 + cc] = v;
          else if (cc < 3072) ((unsigned short*)C2)[(size_t)r * 1024 + (cc - 2048)] = v;
          else                ((unsigned short*)C3)[(size_t)r * 1024 + (cc - 3072)] = v;
        }
      }
    }
}

// ---------------------------------------------------------------------------
// MFMA flash attention v4: round-9 data scheme; 512 blocks, one q-tile each,
// DESCENDING qt so long tiles dispatch first; 2 blocks/CU for latency hiding.
__global__ __launch_bounds__(256) void attn_k(const unsigned short* __restrict__ qg,
                                              const unsigned short* __restrict__ kg,
                                              const unsigned short* __restrict__ vg,
                                              unsigned short* __restrict__ og) {
  __shared__ __align__(16) unsigned short Ks[64 * 128];
  __shared__ __align__(16) unsigned short Vt[128 * 72];
  __shared__ __align__(16) unsigned short Pl[4 * 16 * 72];
  const int tid = threadIdx.x;
  const int nid = xcd_swz(blockIdx.x + (blockIdx.y << 5), 512);
  const int qt = 31 - (nid & 31), h = nid >> 5;
  const int w = tid >> 6, lane = tid & 63;
  const int lr = lane & 15, hi = lane >> 4;
  const int kvh = h >> 1;

  size_t goff[4]; unsigned kdst[4]; int vr[4], vc[4];
#pragma unroll
  for (int i = 0; i < 4; ++i) {
    int e = tid + i * 256;
    int r = e >> 4, c = (e & 15) * 8;
    goff[i] = ((size_t)r * KVm + kvh) * HDm + c;
    kdst[i] = (unsigned)((r * 256 + c * 2) ^ ((r & 7) << 4));
    vr[i] = r; vc[i] = c;
  }

  const int t0 = qt * 64;
  const int ntk = qt + 1;

  bf16x8 qa[4];
  {
    const unsigned short* qrow = qg + ((size_t)(t0 + w * 16 + lr) * Hm + h) * HDm;
#pragma unroll
    for (int ks = 0; ks < 4; ++ks)
      qa[ks] = __builtin_bit_cast(bf16x8, *(const u16x8*)(qrow + ks * 32 + hi * 8));
  }

  f32x4 oa[8] = {};
  float mj[4], lj[4];
#pragma unroll
  for (int j = 0; j < 4; ++j) { mj[j] = -3.0e38f; lj[j] = 0.f; }

  u16x8 kk[4], vv[4];
#pragma unroll
  for (int i = 0; i < 4; ++i) {
    kk[i] = *(const u16x8*)(kg + goff[i]);
    vv[i] = *(const u16x8*)(vg + goff[i]);
  }

  for (int t = 0; t < ntk; ++t) {
    __syncthreads();
#pragma unroll
    for (int i = 0; i < 4; ++i) {
      *(u16x8*)((char*)Ks + kdst[i]) = kk[i];
#pragma unroll
      for (int j = 0; j < 8; ++j) {
        int d = vc[i] + j;
        Vt[d * 72 + (vr[i] ^ (((d >> 3) & 7) << 3))] = vv[i][j];
      }
    }
    if (t + 1 < ntk) {
      size_t add = (size_t)(t + 1) * 64 * KVm * HDm;
#pragma unroll
      for (int i = 0; i < 4; ++i) {
        kk[i] = *(const u16x8*)(kg + goff[i] + add);
        vv[i] = *(const u16x8*)(vg + goff[i] + add);
      }
    }
    __syncthreads();

    const int s0 = t * 64;
    f32x4 s[4] = {};
#pragma unroll
    for (int ks = 0; ks < 4; ++ks)
#pragma unroll
      for (int nt = 0; nt < 4; ++nt) {
        int krow = nt * 16 + lr;
        int kbyte = (krow * 256 + (ks * 32 + hi * 8) * 2) ^ ((krow & 7) << 4);
        bf16x8 kf = __builtin_bit_cast(bf16x8, *(const u16x8*)((char*)Ks + kbyte));
        s[nt] = mfma16x16x32(qa[ks], kf, s[nt]);
      }

    float p[4][4];
    const bool maskt = (t == ntk - 1);
#pragma unroll
    for (int nt = 0; nt < 4; ++nt)
#pragma unroll
      for (int j = 0; j < 4; ++j) {
        float val = s[nt][j] * 0.08838834764831845f;
        if (maskt && (s0 + nt * 16 + lr) > (t0 + w * 16 + hi * 4 + j)) val = -1e30f;
        p[nt][j] = val;
      }

#pragma unroll
    for (int j = 0; j < 4; ++j) {
      float mx = fmaxf(fmaxf(p[0][j], p[1][j]), fmaxf(p[2][j], p[3][j]));
#pragma unroll
      for (int msk = 1; msk < 16; msk <<= 1) mx = fmaxf(mx, __shfl_xor(mx, msk));
      float mnew = fmaxf(mj[j], mx);
      float alpha = __expf(mj[j] - mnew);
      mj[j] = mnew;
      float sum = 0.f;
#pragma unroll
      for (int nt = 0; nt < 4; ++nt) {
        float e = __expf(p[nt][j] - mnew);
        p[nt][j] = e;
        sum += e;
      }
#pragma unroll
      for (int msk = 1; msk < 16; msk <<= 1) sum += __shfl_xor(sum, msk);
      lj[j] = lj[j] * alpha + sum;
#pragma unroll
      for (int nt2 = 0; nt2 < 8; ++nt2) oa[nt2][j] *= alpha;
    }

#pragma unroll
    for (int nt = 0; nt < 4; ++nt)
#pragma unroll
      for (int j = 0; j < 4; ++j)
        Pl[(w * 16 + hi * 4 + j) * 72 + nt * 16 + lr] = f2b(p[nt][j]);
    __builtin_amdgcn_sched_barrier(0);

    bf16x8 pa[2];
#pragma unroll
    for (int ks2 = 0; ks2 < 2; ++ks2)
      pa[ks2] = __builtin_bit_cast(bf16x8,
                 *(const u16x8*)&Pl[(w * 16 + lr) * 72 + ks2 * 32 + hi * 8]);
#pragma unroll
    for (int nt2 = 0; nt2 < 8; ++nt2)
#pragma unroll
      for (int ks2 = 0; ks2 < 2; ++ks2) {
        int d = nt2 * 16 + lr;
        int kv = ks2 * 32 + hi * 8;
        bf16x8 vf = __builtin_bit_cast(bf16x8,
                     *(const u16x8*)&Vt[d * 72 + (kv ^ (((d >> 3) & 7) << 3))]);
        oa[nt2] = mfma16x16x32(pa[ks2], vf, oa[nt2]);
      }
  }

#pragma unroll
  for (int nt2 = 0; nt2 < 8; ++nt2)
#pragma unroll
    for (int j = 0; j < 4; ++j) {
      int row = t0 + w * 16 + hi * 4 + j;
      int d = nt2 * 16 + lr;
      og[((size_t)row * Hm + h) * HDm + d] = f2b(oa[nt2][j] / lj[j]);
    }
}

// ---------------------------------------------------------------------------
extern "C" void kernel_launch(void* const* d_in, const int* in_sizes, int n_in,
                              void* d_out, int out_size, void* d_ws, size_t ws_size,
                              hipStream_t stream) {
  (void)in_sizes; (void)n_in; (void)out_size; (void)ws_size;
  const int*   ids = (const int*)d_in[0];
  const float* emb = (const float*)d_in[1];
  const float* Wq  = (const float*)d_in[2];
  const float* Wk  = (const float*)d_in[3];
  const float* Wv  = (const float*)d_in[4];
  const float* Wo  = (const float*)d_in[5];
  const float* qn  = (const float*)d_in[6];
  const float* kn  = (const float*)d_in[7];
  const float* W1  = (const float*)d_in[8];
  const float* W2  = (const float*)d_in[9];
  const float* W3  = (const float*)d_in[10];
  const float* ln1 = (const float*)d_in[11];
  const float* ln2 = (const float*)d_in[12];
  const float* lnf = (const float*)d_in[13];

  char* p = (char*)d_ws;
  float* xf          = (float*)p;          p += (size_t)Tm * Dm * 4;
  unsigned short* hb = (unsigned short*)p; p += (size_t)Tm * Dm * 2;
  float* cosT        = (float*)p;          p += (size_t)Tm * 64 * 4;
  float* sinT        = (float*)p;          p += (size_t)Tm * 64 * 4;
  unsigned short* qb = (unsigned short*)p; p += (size_t)Tm * Hm * HDm * 2;
  unsigned short* kb = (unsigned short*)p; p += (size_t)Tm * KVm * HDm * 2;
  unsigned short* vb = (unsigned short*)p; p += (size_t)Tm * KVm * HDm * 2;
  unsigned short* ob = (unsigned short*)p; p += (size_t)Tm * Hm * HDm * 2;
  unsigned short* wt = (unsigned short*)p; p += (size_t)Dm * FFm * 2;
  unsigned short* g1 = qb;  // FFN alias: qb..ob span == T*FF*2 exactly

  rope_tables_k<<<Tm, 64, 0, stream>>>(cosT, sinT);
  embed_k<<<Tm, 256, 0, stream>>>(ids, emb, xf);

  for (int l = 0; l < 2; ++l) {
    const float* Wq_l = Wq + (size_t)l * Dm * (Hm * HDm);
    const float* Wk_l = Wk + (size_t)l * Dm * (KVm * HDm);
    const float* Wv_l = Wv + (size_t)l * Dm * (KVm * HDm);
    const float* Wo_l = Wo + (size_t)l * (Hm * HDm) * Dm;
    const float* W1_l = W1 + (size_t)l * Dm * FFm;
    const float* W2_l = W2 + (size_t)l * Dm * FFm;
    const float* W3_l = W3 + (size_t)l * FFm * Dm;

    rmsnorm_k<<<Tm, 256, 0, stream>>>(xf, ln1 + (size_t)l * Dm, hb);

    cvtT_k<<<dim3((Hm * HDm) / 64, Dm / 64), 256, 0, stream>>>(Wq_l, wt, Dm, Hm * HDm);
    cvtT_k<<<dim3((KVm * HDm) / 64, Dm / 64), 256, 0, stream>>>(
        Wk_l, wt + (size_t)2048 * Dm, Dm, KVm * HDm);
    cvtT_k<<<dim3((KVm * HDm) / 64, Dm / 64), 256, 0, stream>>>(
        Wv_l, wt + (size_t)3072 * Dm, Dm, KVm * HDm);
    gemm256_k<3, false><<<dim3(Tm / 256, QKVN / 256), 512, 0, stream>>>(
        hb, wt, qb, kb, vb, QKVN, Dm, 0);

    qknorm_rope_k<<<(Tm * Hm) / 4, 256, 0, stream>>>(qb, qn + (size_t)l * HDm, cosT, sinT, Hm);
    qknorm_rope_k<<<(Tm * KVm) / 4, 256, 0, stream>>>(kb, kn + (size_t)l * HDm, cosT, sinT, KVm);

    attn_k<<<dim3(32, 16), 256, 0, stream>>>(qb, kb, vb, ob);

    cvtT_k<<<dim3(Dm / 64, (Hm * HDm) / 64), 256, 0, stream>>>(Wo_l, wt, Hm * HDm, Dm);
    gemm2p_k<1, false><<<dim3(Tm / 128, Dm / 128), 256, 0, stream>>>(
        ob, wt, xf, nullptr, nullptr, Dm, Hm * HDm, Hm * HDm, 0);

    rmsnorm_k<<<Tm, 256, 0, stream>>>(xf, ln2 + (size_t)l * Dm, hb);

    cvtT_k<<<dim3(FFm / 64, Dm / 64), 256, 0, stream>>>(W1_l, wt, Dm, FFm);
    gemm256_k<0, false><<<dim3(Tm / 256, FFm / 256), 512, 0, stream>>>(
        hb, wt, g1, nullptr, nullptr, FFm, Dm, 0);
    cvtT_k<<<dim3(FFm / 64, Dm / 64), 256, 0, stream>>>(W2_l, wt, Dm, FFm);
    gemm256_k<2, false><<<dim3(Tm / 256, FFm / 256), 512, 0, stream>>>(
        hb, wt, g1, nullptr, nullptr, FFm, Dm, 0);
    cvtT_k<<<dim3(Dm / 64, FFm / 64), 256, 0, stream>>>(W3_l, wt, FFm, Dm);
    // W3 split-K=3: 768 blocks, fp32 atomicAdd into the residual
    gemm2p_k<4, false><<<dim3(Tm / 128, Dm / 128, 3), 256, 0, stream>>>(
        g1, wt, xf, nullptr, nullptr, Dm, 2048, FFm, 0);
  }

  rmsnorm_k<<<Tm, 256, 0, stream>>>(xf, lnf, hb);

  // logits: 4 bf16 chunks sized for whole grid-rounds (256/256/256/232 blocks)
  unsigned short* embB = qb;
  const int chunks[4] = {8192, 8192, 8192, 7424};
  int off = 0;
  for (int c = 0; c < 4; ++c) {
    const int rows = chunks[c];
    cvt_flat_k<<<rows, 256, 0, stream>>>(emb + (size_t)off * Dm, embB);
    gemm256_k<0, true><<<dim3(Tm / 256, rows / 256), 512, 0, stream>>>(
        hb, embB, d_out, nullptr, nullptr, Vm, Dm, off);
    off += rows;
  }
}

// Round 15
// 1407.970 us; speedup vs baseline: 1.0727x; 1.0727x over previous
//
#include <hip/hip_runtime.h>
#include <math.h>

typedef float f32x4 __attribute__((ext_vector_type(4)));
typedef __bf16 bf16x8 __attribute__((ext_vector_type(8)));
typedef unsigned short u16x8 __attribute__((ext_vector_type(8)));

static constexpr int Dm  = 2048;
static constexpr int Tm  = 2048;
static constexpr int Hm  = 16;
static constexpr int KVm = 8;
static constexpr int HDm = 128;
static constexpr int FFm = 6144;
static constexpr int Vm  = 32000;
static constexpr int QKVN = 4096;

__device__ __forceinline__ float b2f(unsigned short u) {
  unsigned int x = ((unsigned int)u) << 16;
  return __builtin_bit_cast(float, x);
}
__device__ __forceinline__ unsigned short f2b(float f) {
  return __builtin_bit_cast(unsigned short, (__bf16)f);   // v_cvt RTNE
}
__device__ __forceinline__ f32x4 mfma16x16x32(bf16x8 a, bf16x8 b, f32x4 c) {
  return __builtin_amdgcn_mfma_f32_16x16x32_bf16(a, b, c, 0, 0, 0);
}

// async global->LDS, 16B/lane; LDS dest = wave-uniform base + lane*16
__device__ __forceinline__ void gload16(const void* g, void* lds) {
  __builtin_amdgcn_global_load_lds(
      (const __attribute__((address_space(1))) unsigned int*)g,
      (__attribute__((address_space(3))) unsigned int*)lds, 16, 0, 0);
}

// bijective chunked XCD swizzle (m204)
__device__ __forceinline__ int xcd_swz(int o, int nwg) {
  int q = nwg >> 3, r8 = nwg & 7;
  int xcd = o & 7, pos = o >> 3;
  return (xcd < r8) ? xcd * (q + 1) + pos : r8 * (q + 1) + (xcd - r8) * q + pos;
}

// ---------------------------------------------------------------------------
__global__ void rope_tables_k(float* __restrict__ cosT, float* __restrict__ sinT) {
  int t = blockIdx.x;
  int i = threadIdx.x;      // 0..63
  double inv = pow(1000000.0, -(double)i / 64.0);
  double ang = (double)t * inv;
  cosT[t * 64 + i] = (float)cos(ang);
  sinT[t * 64 + i] = (float)sin(ang);
}

__global__ __launch_bounds__(256) void embed_k(const int* __restrict__ ids,
                                               const float* __restrict__ emb,
                                               float* __restrict__ x) {
  int t = blockIdx.x;
  int d0 = threadIdx.x * 8;
  int id = ids[t];
  const float* src = emb + (size_t)id * Dm + d0;
  float* dst = x + (size_t)t * Dm + d0;
  *(f32x4*)dst       = *(const f32x4*)src;
  *(f32x4*)(dst + 4) = *(const f32x4*)(src + 4);
}

// fp32 -> bf16 flat convert, 2048 elems per block
__global__ __launch_bounds__(256) void cvt_flat_k(const float* __restrict__ src,
                                                  unsigned short* __restrict__ dst) {
  size_t i = ((size_t)blockIdx.x * 256 + threadIdx.x) * 8;
  f32x4 a = *(const f32x4*)(src + i);
  f32x4 b = *(const f32x4*)(src + i + 4);
  u16x8 o;
  o[0] = f2b(a.x); o[1] = f2b(a.y); o[2] = f2b(a.z); o[3] = f2b(a.w);
  o[4] = f2b(b.x); o[5] = f2b(b.y); o[6] = f2b(b.z); o[7] = f2b(b.w);
  *(u16x8*)(dst + i) = o;
}

__global__ __launch_bounds__(256) void rmsnorm_k(const float* __restrict__ x,
                                                 const float* __restrict__ g,
                                                 unsigned short* __restrict__ y) {
  int t = blockIdx.x;
  const float* xr = x + (size_t)t * Dm;
  float vals[8];
  float s = 0.f;
#pragma unroll
  for (int i = 0; i < 8; ++i) {
    float vv = xr[threadIdx.x + i * 256];
    vals[i] = vv;
    s += vv * vv;
  }
#pragma unroll
  for (int off = 32; off; off >>= 1) s += __shfl_xor(s, off);
  __shared__ float red[4];
  if ((threadIdx.x & 63) == 0) red[threadIdx.x >> 6] = s;
  __syncthreads();
  s = (red[0] + red[1]) + (red[2] + red[3]);
  float r = rsqrtf(s * (1.f / Dm) + 1e-6f);
  unsigned short* yr = y + (size_t)t * Dm;
#pragma unroll
  for (int i = 0; i < 8; ++i) {
    int d = threadIdx.x + i * 256;
    yr[d] = f2b(vals[i] * r * g[d]);
  }
}

__global__ __launch_bounds__(256) void qknorm_rope_k(unsigned short* __restrict__ q,
                                                     const float* __restrict__ nrm,
                                                     const float* __restrict__ cosT,
                                                     const float* __restrict__ sinT,
                                                     int nheads) {
  int gw = (int)((blockIdx.x * blockDim.x + threadIdx.x) >> 6);
  int lane = threadIdx.x & 63;
  int t = gw / nheads, h = gw % nheads;
  unsigned short* row = q + ((size_t)t * nheads + h) * HDm;
  float x1 = b2f(row[lane]);
  float x2 = b2f(row[lane + 64]);
  float s = x1 * x1 + x2 * x2;
#pragma unroll
  for (int off = 32; off; off >>= 1) s += __shfl_xor(s, off);
  float r = rsqrtf(s * (1.f / HDm) + 1e-6f);
  float y1 = x1 * r * nrm[lane];
  float y2 = x2 * r * nrm[lane + 64];
  float c = cosT[t * 64 + lane];
  float sn = sinT[t * 64 + lane];
  row[lane]      = f2b(y1 * c - y2 * sn);
  row[lane + 64] = f2b(y2 * c + y1 * sn);
}

// Weight convert+transpose: W fp32 [K][N] -> Wt bf16 [N][K]
__global__ __launch_bounds__(256) void cvtT_k(const float* __restrict__ W,
                                              unsigned short* __restrict__ Wt,
                                              int K, int N) {
  __shared__ __align__(16) unsigned short tile[64][68];
  const int n0 = blockIdx.x * 64, k0 = blockIdx.y * 64;
  const int tid = threadIdx.x;
#pragma unroll
  for (int i = 0; i < 4; ++i) {
    int e = tid + i * 256;
    int r = e >> 4, c4 = (e & 15) * 4;
    f32x4 v = *(const f32x4*)(W + (size_t)(k0 + r) * N + n0 + c4);
    tile[r][c4 + 0] = f2b(v.x);
    tile[r][c4 + 1] = f2b(v.y);
    tile[r][c4 + 2] = f2b(v.z);
    tile[r][c4 + 3] = f2b(v.w);
  }
  __syncthreads();
#pragma unroll
  for (int i = 0; i < 2; ++i) {
    int e = tid + i * 256;
    int rr = e >> 3, cc = (e & 7) * 8;
    u16x8 o;
#pragma unroll
    for (int j = 0; j < 8; ++j) o[j] = tile[cc + j][rr];
    *(u16x8*)(Wt + (size_t)(n0 + rr) * K + k0 + cc) = o;
  }
}

// ---------------------------------------------------------------------------
// 2-phase 128^2 GEMM (round-12 proven; ld = row stride >= K)
template <int EPI, bool OUTF32>
__global__ __launch_bounds__(256) void gemm2p_k(const unsigned short* __restrict__ A,
                                                const unsigned short* __restrict__ B,
                                                void* __restrict__ C,
                                                void* __restrict__ C2,
                                                void* __restrict__ C3,
                                                int N, int K, int ld, int cOff) {
  __shared__ __align__(16) unsigned short lds[2][2][128 * 64];   // 64 KiB
  const int tid = threadIdx.x;
  const int nwg = gridDim.x * gridDim.y;
  const int nid = xcd_swz(blockIdx.x + gridDim.x * blockIdx.y, nwg);
  const int bm = nid % gridDim.x, bn = nid / gridDim.x;
  const int w = tid >> 6, lane = tid & 63;
  const int wm = (w >> 1) * 64, wn = (w & 1) * 64;
  const int lr = lane & 15, hi = lane >> 4;
  const int rowA0 = bm * 128, colB0 = bn * 128;
  const int nk = K >> 6;

  const int srow = lane >> 3;            // row within 8-row chunk
  const int ulog = (lane & 7) ^ srow;    // pre-swizzled logical k-unit
  const unsigned short* gA = A + (size_t)(rowA0 + w * 32 + srow) * ld + ulog * 8;
  const unsigned short* gB = B + (size_t)(colB0 + w * 32 + srow) * ld + ulog * 8;

  int uu[2];
  uu[0] = ((0 + hi) ^ (lr & 7)) * 8;
  uu[1] = ((4 + hi) ^ (lr & 7)) * 8;

  f32x4 acc[4][4] = {};

  auto stage8 = [&](int buf, int k0) {
    unsigned short* lA = &lds[buf][0][(w * 32) * 64];
    unsigned short* lB = &lds[buf][1][(w * 32) * 64];
#pragma unroll
    for (int i = 0; i < 4; ++i) {
      gload16(gA + (size_t)(i * 8) * ld + k0, lA + i * 8 * 64);
      gload16(gB + (size_t)(i * 8) * ld + k0, lB + i * 8 * 64);
    }
  };

  stage8(0, 0);
  asm volatile("s_waitcnt vmcnt(0)" ::: "memory");
  __builtin_amdgcn_s_barrier();

  for (int kt = 0; kt < nk; ++kt) {
    const int cur = kt & 1;
    if (kt + 1 < nk) stage8(cur ^ 1, (kt + 1) << 6);   // issue early

    const unsigned short* Ac = &lds[cur][0][0];
    const unsigned short* Bc = &lds[cur][1][0];
    bf16x8 av[4][2], bv[4][2];
#pragma unroll
    for (int m = 0; m < 4; ++m) {
      int rb = (wm + m * 16 + lr) * 64;
#pragma unroll
      for (int ks = 0; ks < 2; ++ks)
        av[m][ks] = *(const bf16x8*)&Ac[rb + uu[ks]];
    }
#pragma unroll
    for (int n = 0; n < 4; ++n) {
      int rb = (wn + n * 16 + lr) * 64;
#pragma unroll
      for (int ks = 0; ks < 2; ++ks)
        bv[n][ks] = *(const bf16x8*)&Bc[rb + uu[ks]];
    }
    __builtin_amdgcn_s_setprio(1);
#pragma unroll
    for (int m = 0; m < 4; ++m)
#pragma unroll
      for (int n = 0; n < 4; ++n)
#pragma unroll
        for (int ks = 0; ks < 2; ++ks)
          acc[m][n] = mfma16x16x32(av[m][ks], bv[n][ks], acc[m][n]);
    __builtin_amdgcn_s_setprio(0);

    asm volatile("s_waitcnt vmcnt(0) lgkmcnt(0)" ::: "memory");
    __builtin_amdgcn_sched_barrier(0);
    __builtin_amdgcn_s_barrier();
  }

  const int r0 = rowA0 + wm + hi * 4;
  const int c0 = wn + lr;
#pragma unroll
  for (int m = 0; m < 4; ++m)
#pragma unroll
    for (int n = 0; n < 4; ++n) {
      const int cc = colB0 + c0 + n * 16;
#pragma unroll
      for (int j = 0; j < 4; ++j) {
        int r = r0 + m * 16 + j;
        if (EPI == 0) {
          size_t idx = (size_t)r * N + cOff + cc;
          if (OUTF32) ((float*)C)[idx] = acc[m][n][j];
          else        ((unsigned short*)C)[idx] = f2b(acc[m][n][j]);
        } else if (EPI == 1) {
          ((float*)C)[(size_t)r * N + cc] += acc[m][n][j];
        } else if (EPI == 2) {
          unsigned short* Cb = (unsigned short*)C;
          size_t idx = (size_t)r * N + cc;
          float gg = b2f(Cb[idx]);
          gg = gg / (1.f + __expf(-gg));
          Cb[idx] = f2b(gg * acc[m][n][j]);
        } else {  // EPI==3: QKV split-store
          unsigned short v = f2b(acc[m][n][j]);
          if (cc < 2048)      ((unsigned short*)C )[(size_t)r * 2048 + cc] = v;
          else if (cc < 3072) ((unsigned short*)C2)[(size_t)r * 1024 + (cc - 2048)] = v;
          else                ((unsigned short*)C3)[(size_t)r * 1024 + (cc - 3072)] = v;
        }
      }
    }
}

// ---------------------------------------------------------------------------
// 256^2 8-phase GEMM (round-13 proven, unchanged)
#define LDA256(MH)                                                             \
  _Pragma("unroll") for (int m_ = 0; m_ < 4; ++m_)                             \
  _Pragma("unroll") for (int ks_ = 0; ks_ < 2; ++ks_)                          \
    av[m_][ks_] = *(const bf16x8*)&Ac[aBase + (MH) * 4096 + m_ * 1024 + uu[ks_]];
#define LDB256(NH)                                                             \
  _Pragma("unroll") for (int n_ = 0; n_ < 2; ++n_)                             \
  _Pragma("unroll") for (int ks_ = 0; ks_ < 2; ++ks_)                          \
    bv[n_][ks_] = *(const bf16x8*)&Bc[bBase + (NH) * 2048 + n_ * 1024 + uu[ks_]];
#define MMA256(MH, NH)                                                         \
  __builtin_amdgcn_s_setprio(1);                                               \
  _Pragma("unroll") for (int m_ = 0; m_ < 4; ++m_)                             \
  _Pragma("unroll") for (int n_ = 0; n_ < 2; ++n_)                             \
  _Pragma("unroll") for (int ks_ = 0; ks_ < 2; ++ks_)                          \
    acc[(MH) * 4 + m_][(NH) * 2 + n_] = mfma16x16x32(                          \
        av[m_][ks_], bv[n_][ks_], acc[(MH) * 4 + m_][(NH) * 2 + n_]);          \
  __builtin_amdgcn_s_setprio(0);
#define SYNCV                                                                  \
  asm volatile("s_waitcnt vmcnt(4)" ::: "memory");                             \
  __builtin_amdgcn_s_barrier();                                                \
  asm volatile("s_waitcnt lgkmcnt(0)" ::: "memory");                           \
  __builtin_amdgcn_sched_barrier(0);
#define SYNCNV                                                                 \
  __builtin_amdgcn_s_barrier();                                                \
  asm volatile("s_waitcnt lgkmcnt(0)" ::: "memory");                           \
  __builtin_amdgcn_sched_barrier(0);
#define ENDPH __builtin_amdgcn_s_barrier();

template <int EPI, bool OUTF32>
__global__ __launch_bounds__(512) void gemm256_k(const unsigned short* __restrict__ A,
                                                 const unsigned short* __restrict__ B,
                                                 void* __restrict__ C,
                                                 void* __restrict__ C2,
                                                 void* __restrict__ C3,
                                                 int N, int K, int cOff) {
  __shared__ __align__(16) unsigned short lds[2][2][256 * 64];   // 128 KiB
  const int tid = threadIdx.x;
  const int nwg = gridDim.x * gridDim.y;
  const int nid = xcd_swz(blockIdx.x + gridDim.x * blockIdx.y, nwg);
  const int bm = nid % gridDim.x, bn = nid / gridDim.x;
  const int w = tid >> 6, lane = tid & 63;
  const int wr = w >> 2, wc = w & 3;
  const int lr = lane & 15, hi = lane >> 4;
  const int rowA0 = bm * 256, colB0 = bn * 256;
  const int nk = K >> 6;

  const int srow = lane >> 3;
  const int ulog = (lane & 7) ^ srow;
  const int eaR = (w < 4) ? w * 16 : 128 + (w - 4) * 16;
  const int laR = eaR + 64;
  const int ebR = (w >> 1) * 64 + (w & 1) * 16;
  const int lbR = ebR + 32;
  const unsigned short* gAt = A + (size_t)rowA0 * K + ulog * 8;
  const unsigned short* gBt = B + (size_t)colB0 * K + ulog * 8;

  int uu[2];
  uu[0] = ((0 + hi) ^ (lr & 7)) * 8;
  uu[1] = ((4 + hi) ^ (lr & 7)) * 8;
  const int aBase = (wr * 128 + lr) * 64;
  const int bBase = (wc * 64 + lr) * 64;

  f32x4 acc[8][4] = {};
  bf16x8 av[4][2], bv[2][2];

  auto stage2 = [&](const unsigned short* g, int rbase, unsigned short* l, int k0) {
    gload16(g + (size_t)(rbase + srow) * K + k0, l + rbase * 64);
    gload16(g + (size_t)(rbase + 8 + srow) * K + k0, l + (rbase + 8) * 64);
  };

  stage2(gAt, eaR, &lds[0][0][0], 0);
  stage2(gBt, ebR, &lds[0][1][0], 0);
  stage2(gBt, lbR, &lds[0][1][0], 0);
  stage2(gAt, laR, &lds[0][0][0], 0);
  asm volatile("s_waitcnt vmcnt(0)" ::: "memory");
  __builtin_amdgcn_s_barrier();

  for (int kt = 0; kt < nk; ++kt) {
    unsigned short* Ac = &lds[kt & 1][0][0];
    unsigned short* Bc = &lds[kt & 1][1][0];
    unsigned short* An = &lds[(kt + 1) & 1][0][0];
    unsigned short* Bn = &lds[(kt + 1) & 1][1][0];
    const int k0n = (kt + 1) << 6;
    const bool more = (kt + 1) < nk;

    LDA256(0) LDB256(0)
    if (more) stage2(gAt, eaR, An, k0n);
    SYNCV MMA256(0, 0) ENDPH
    LDB256(1)
    if (more) stage2(gBt, ebR, Bn, k0n);
    SYNCV MMA256(0, 1) ENDPH
    LDA256(1)
    if (more) stage2(gBt, lbR, Bn, k0n);
    SYNCNV MMA256(1, 1) ENDPH
    LDB256(0)
    if (more) stage2(gAt, laR, An, k0n);
    SYNCV MMA256(1, 0) ENDPH
  }

  const int r0 = rowA0 + wr * 128 + hi * 4;
  const int c0 = colB0 + wc * 64 + lr;
#pragma unroll
  for (int mi = 0; mi < 8; ++mi)
#pragma unroll
    for (int n = 0; n < 4; ++n) {
      const int cc = c0 + n * 16;
#pragma unroll
      for (int j = 0; j < 4; ++j) {
        int r = r0 + mi * 16 + j;
        if (EPI == 0) {
          size_t idx = (size_t)r * N + cOff + cc;
          if (OUTF32) ((float*)C)[idx] = acc[mi][n][j];
          else        ((unsigned short*)C)[idx] = f2b(acc[mi][n][j]);
        } else if (EPI == 2) {
          unsigned short* Cb = (unsigned short*)C;
          size_t idx = (size_t)r * N + cc;
          float gg = b2f(Cb[idx]);
          gg = gg / (1.f + __expf(-gg));
          Cb[idx] = f2b(gg * acc[mi][n][j]);
        } else {  // EPI==3: QKV split-store
          unsigned short v = f2b(acc[mi][n][j]);
          if (cc < 2048)      ((unsigned short*)C )[(size_t)r * 2048 + cc] = v;
          else if (cc < 3072) ((unsigned short*)C2)[(size_t)r * 1024 + (cc - 2048)] = v;
          else                ((unsigned short*)C3)[(size_t)r * 1024 + (cc - 3072)] = v;
        }
      }
    }
}

// ---------------------------------------------------------------------------
// MFMA flash attention v5: r14-proven single-pass body; pairing FIXED so
// co-resident blocks (o, o+256) -> (nid, nid+32) get COMPLEMENTARY q-tiles:
// u=nid&63, h=((nid>>6)<<1)|(u>>5), qt = u<32 ? u : 63-u.
// Every CU hosts qt=p and qt=31-p (33 units), same kvh (L2 locality).
__global__ __launch_bounds__(256) void attn_k(const unsigned short* __restrict__ qg,
                                              const unsigned short* __restrict__ kg,
                                              const unsigned short* __restrict__ vg,
                                              unsigned short* __restrict__ og) {
  __shared__ __align__(16) unsigned short Ks[64 * 128];
  __shared__ __align__(16) unsigned short Vt[128 * 72];
  __shared__ __align__(16) unsigned short Pl[4 * 16 * 72];
  const int tid = threadIdx.x;
  const int nid = xcd_swz(blockIdx.x + (blockIdx.y << 5), 512);
  const int u = nid & 63;
  const int h = ((nid >> 6) << 1) | (u >> 5);
  const int qt = (u < 32) ? u : 63 - u;
  const int w = tid >> 6, lane = tid & 63;
  const int lr = lane & 15, hi = lane >> 4;
  const int kvh = h >> 1;

  size_t goff[4]; unsigned kdst[4]; int vr[4], vc[4];
#pragma unroll
  for (int i = 0; i < 4; ++i) {
    int e = tid + i * 256;
    int r = e >> 4, c = (e & 15) * 8;
    goff[i] = ((size_t)r * KVm + kvh) * HDm + c;
    kdst[i] = (unsigned)((r * 256 + c * 2) ^ ((r & 7) << 4));
    vr[i] = r; vc[i] = c;
  }

  const int t0 = qt * 64;
  const int ntk = qt + 1;

  bf16x8 qa[4];
  {
    const unsigned short* qrow = qg + ((size_t)(t0 + w * 16 + lr) * Hm + h) * HDm;
#pragma unroll
    for (int ks = 0; ks < 4; ++ks)
      qa[ks] = __builtin_bit_cast(bf16x8, *(const u16x8*)(qrow + ks * 32 + hi * 8));
  }

  f32x4 oa[8] = {};
  float mj[4], lj[4];
#pragma unroll
  for (int j = 0; j < 4; ++j) { mj[j] = -3.0e38f; lj[j] = 0.f; }

  u16x8 kk[4], vv[4];
#pragma unroll
  for (int i = 0; i < 4; ++i) {
    kk[i] = *(const u16x8*)(kg + goff[i]);
    vv[i] = *(const u16x8*)(vg + goff[i]);
  }

  for (int t = 0; t < ntk; ++t) {
    __syncthreads();
#pragma unroll
    for (int i = 0; i < 4; ++i) {
      *(u16x8*)((char*)Ks + kdst[i]) = kk[i];
#pragma unroll
      for (int j = 0; j < 8; ++j) {
        int d = vc[i] + j;
        Vt[d * 72 + (vr[i] ^ (((d >> 3) & 7) << 3))] = vv[i][j];
      }
    }
    if (t + 1 < ntk) {
      size_t add = (size_t)(t + 1) * 64 * KVm * HDm;
#pragma unroll
      for (int i = 0; i < 4; ++i) {
        kk[i] = *(const u16x8*)(kg + goff[i] + add);
        vv[i] = *(const u16x8*)(vg + goff[i] + add);
      }
    }
    __syncthreads();

    const int s0 = t * 64;
    f32x4 s[4] = {};
#pragma unroll
    for (int ks = 0; ks < 4; ++ks)
#pragma unroll
      for (int nt = 0; nt < 4; ++nt) {
        int krow = nt * 16 + lr;
        int kbyte = (krow * 256 + (ks * 32 + hi * 8) * 2) ^ ((krow & 7) << 4);
        bf16x8 kf = __builtin_bit_cast(bf16x8, *(const u16x8*)((char*)Ks + kbyte));
        s[nt] = mfma16x16x32(qa[ks], kf, s[nt]);
      }

    float p[4][4];
    const bool maskt = (t == ntk - 1);
#pragma unroll
    for (int nt = 0; nt < 4; ++nt)
#pragma unroll
      for (int j = 0; j < 4; ++j) {
        float val = s[nt][j] * 0.08838834764831845f;
        if (maskt && (s0 + nt * 16 + lr) > (t0 + w * 16 + hi * 4 + j)) val = -1e30f;
        p[nt][j] = val;
      }

#pragma unroll
    for (int j = 0; j < 4; ++j) {
      float mx = fmaxf(fmaxf(p[0][j], p[1][j]), fmaxf(p[2][j], p[3][j]));
#pragma unroll
      for (int msk = 1; msk < 16; msk <<= 1) mx = fmaxf(mx, __shfl_xor(mx, msk));
      float mnew = fmaxf(mj[j], mx);
      float alpha = __expf(mj[j] - mnew);
      mj[j] = mnew;
      float sum = 0.f;
#pragma unroll
      for (int nt = 0; nt < 4; ++nt) {
        float e = __expf(p[nt][j] - mnew);
        p[nt][j] = e;
        sum += e;
      }
#pragma unroll
      for (int msk = 1; msk < 16; msk <<= 1) sum += __shfl_xor(sum, msk);
      lj[j] = lj[j] * alpha + sum;
#pragma unroll
      for (int nt2 = 0; nt2 < 8; ++nt2) oa[nt2][j] *= alpha;
    }

#pragma unroll
    for (int nt = 0; nt < 4; ++nt)
#pragma unroll
      for (int j = 0; j < 4; ++j)
        Pl[(w * 16 + hi * 4 + j) * 72 + nt * 16 + lr] = f2b(p[nt][j]);
    __builtin_amdgcn_sched_barrier(0);

    bf16x8 pa[2];
#pragma unroll
    for (int ks2 = 0; ks2 < 2; ++ks2)
      pa[ks2] = __builtin_bit_cast(bf16x8,
                 *(const u16x8*)&Pl[(w * 16 + lr) * 72 + ks2 * 32 + hi * 8]);
#pragma unroll
    for (int nt2 = 0; nt2 < 8; ++nt2)
#pragma unroll
      for (int ks2 = 0; ks2 < 2; ++ks2) {
        int d = nt2 * 16 + lr;
        int kv = ks2 * 32 + hi * 8;
        bf16x8 vf = __builtin_bit_cast(bf16x8,
                     *(const u16x8*)&Vt[d * 72 + (kv ^ (((d >> 3) & 7) << 3))]);
        oa[nt2] = mfma16x16x32(pa[ks2], vf, oa[nt2]);
      }
  }

#pragma unroll
  for (int nt2 = 0; nt2 < 8; ++nt2)
#pragma unroll
    for (int j = 0; j < 4; ++j) {
      int row = t0 + w * 16 + hi * 4 + j;
      int d = nt2 * 16 + lr;
      og[((size_t)row * Hm + h) * HDm + d] = f2b(oa[nt2][j] / lj[j]);
    }
}

// ---------------------------------------------------------------------------
extern "C" void kernel_launch(void* const* d_in, const int* in_sizes, int n_in,
                              void* d_out, int out_size, void* d_ws, size_t ws_size,
                              hipStream_t stream) {
  (void)in_sizes; (void)n_in; (void)out_size; (void)ws_size;
  const int*   ids = (const int*)d_in[0];
  const float* emb = (const float*)d_in[1];
  const float* Wq  = (const float*)d_in[2];
  const float* Wk  = (const float*)d_in[3];
  const float* Wv  = (const float*)d_in[4];
  const float* Wo  = (const float*)d_in[5];
  const float* qn  = (const float*)d_in[6];
  const float* kn  = (const float*)d_in[7];
  const float* W1  = (const float*)d_in[8];
  const float* W2  = (const float*)d_in[9];
  const float* W3  = (const float*)d_in[10];
  const float* ln1 = (const float*)d_in[11];
  const float* ln2 = (const float*)d_in[12];
  const float* lnf = (const float*)d_in[13];

  char* p = (char*)d_ws;
  float* xf          = (float*)p;          p += (size_t)Tm * Dm * 4;
  unsigned short* hb = (unsigned short*)p; p += (size_t)Tm * Dm * 2;
  float* cosT        = (float*)p;          p += (size_t)Tm * 64 * 4;
  float* sinT        = (float*)p;          p += (size_t)Tm * 64 * 4;
  unsigned short* qb = (unsigned short*)p; p += (size_t)Tm * Hm * HDm * 2;
  unsigned short* kb = (unsigned short*)p; p += (size_t)Tm * KVm * HDm * 2;
  unsigned short* vb = (unsigned short*)p; p += (size_t)Tm * KVm * HDm * 2;
  unsigned short* ob = (unsigned short*)p; p += (size_t)Tm * Hm * HDm * 2;
  unsigned short* wt = (unsigned short*)p; p += (size_t)Dm * FFm * 2;
  unsigned short* g1 = qb;  // FFN alias: qb..ob span == T*FF*2 exactly

  rope_tables_k<<<Tm, 64, 0, stream>>>(cosT, sinT);
  embed_k<<<Tm, 256, 0, stream>>>(ids, emb, xf);

  for (int l = 0; l < 2; ++l) {
    const float* Wq_l = Wq + (size_t)l * Dm * (Hm * HDm);
    const float* Wk_l = Wk + (size_t)l * Dm * (KVm * HDm);
    const float* Wv_l = Wv + (size_t)l * Dm * (KVm * HDm);
    const float* Wo_l = Wo + (size_t)l * (Hm * HDm) * Dm;
    const float* W1_l = W1 + (size_t)l * Dm * FFm;
    const float* W2_l = W2 + (size_t)l * Dm * FFm;
    const float* W3_l = W3 + (size_t)l * FFm * Dm;

    rmsnorm_k<<<Tm, 256, 0, stream>>>(xf, ln1 + (size_t)l * Dm, hb);

    cvtT_k<<<dim3((Hm * HDm) / 64, Dm / 64), 256, 0, stream>>>(Wq_l, wt, Dm, Hm * HDm);
    cvtT_k<<<dim3((KVm * HDm) / 64, Dm / 64), 256, 0, stream>>>(
        Wk_l, wt + (size_t)2048 * Dm, Dm, KVm * HDm);
    cvtT_k<<<dim3((KVm * HDm) / 64, Dm / 64), 256, 0, stream>>>(
        Wv_l, wt + (size_t)3072 * Dm, Dm, KVm * HDm);
    gemm256_k<3, false><<<dim3(Tm / 256, QKVN / 256), 512, 0, stream>>>(
        hb, wt, qb, kb, vb, QKVN, Dm, 0);

    qknorm_rope_k<<<(Tm * Hm) / 4, 256, 0, stream>>>(qb, qn + (size_t)l * HDm, cosT, sinT, Hm);
    qknorm_rope_k<<<(Tm * KVm) / 4, 256, 0, stream>>>(kb, kn + (size_t)l * HDm, cosT, sinT, KVm);

    attn_k<<<dim3(32, 16), 256, 0, stream>>>(qb, kb, vb, ob);

    cvtT_k<<<dim3(Dm / 64, (Hm * HDm) / 64), 256, 0, stream>>>(Wo_l, wt, Hm * HDm, Dm);
    gemm2p_k<1, false><<<dim3(Tm / 128, Dm / 128), 256, 0, stream>>>(
        ob, wt, xf, nullptr, nullptr, Dm, Hm * HDm, Hm * HDm, 0);

    rmsnorm_k<<<Tm, 256, 0, stream>>>(xf, ln2 + (size_t)l * Dm, hb);

    cvtT_k<<<dim3(FFm / 64, Dm / 64), 256, 0, stream>>>(W1_l, wt, Dm, FFm);
    gemm256_k<0, false><<<dim3(Tm / 256, FFm / 256), 512, 0, stream>>>(
        hb, wt, g1, nullptr, nullptr, FFm, Dm, 0);
    cvtT_k<<<dim3(FFm / 64, Dm / 64), 256, 0, stream>>>(W2_l, wt, Dm, FFm);
    gemm256_k<2, false><<<dim3(Tm / 256, FFm / 256), 512, 0, stream>>>(
        hb, wt, g1, nullptr, nullptr, FFm, Dm, 0);
    cvtT_k<<<dim3(Dm / 64, FFm / 64), 256, 0, stream>>>(W3_l, wt, FFm, Dm);
    gemm2p_k<1, false><<<dim3(Tm / 128, Dm / 128), 256, 0, stream>>>(
        g1, wt, xf, nullptr, nullptr, Dm, FFm, FFm, 0);
  }

  rmsnorm_k<<<Tm, 256, 0, stream>>>(xf, lnf, hb);

  // logits: 4 bf16 chunks sized for whole grid-rounds (256/256/256/232 blocks)
  unsigned short* embB = qb;
  const int chunks[4] = {8192, 8192, 8192, 7424};
  int off = 0;
  for (int c = 0; c < 4; ++c) {
    const int rows = chunks[c];
    cvt_flat_k<<<rows, 256, 0, stream>>>(emb + (size_t)off * Dm, embB);
    gemm256_k<0, true><<<dim3(Tm / 256, rows / 256), 512, 0, stream>>>(
        hb, embB, d_out, nullptr, nullptr, Vm, Dm, off);
    off += rows;
  }
}

// Round 16
// 1380.173 us; speedup vs baseline: 1.0943x; 1.0201x over previous
//
#include <hip/hip_runtime.h>
#include <math.h>

typedef float f32x4 __attribute__((ext_vector_type(4)));
typedef __bf16 bf16x8 __attribute__((ext_vector_type(8)));
typedef unsigned short u16x8 __attribute__((ext_vector_type(8)));

static constexpr int Dm  = 2048;
static constexpr int Tm  = 2048;
static constexpr int Hm  = 16;
static constexpr int KVm = 8;
static constexpr int HDm = 128;
static constexpr int FFm = 6144;
static constexpr int Vm  = 32000;
static constexpr int QKVN = 4096;

__device__ __forceinline__ float b2f(unsigned short u) {
  unsigned int x = ((unsigned int)u) << 16;
  return __builtin_bit_cast(float, x);
}
__device__ __forceinline__ unsigned short f2b(float f) {
  return __builtin_bit_cast(unsigned short, (__bf16)f);   // v_cvt RTNE
}
__device__ __forceinline__ f32x4 mfma16x16x32(bf16x8 a, bf16x8 b, f32x4 c) {
  return __builtin_amdgcn_mfma_f32_16x16x32_bf16(a, b, c, 0, 0, 0);
}

// async global->LDS, 16B/lane; LDS dest = wave-uniform base + lane*16
__device__ __forceinline__ void gload16(const void* g, void* lds) {
  __builtin_amdgcn_global_load_lds(
      (const __attribute__((address_space(1))) unsigned int*)g,
      (__attribute__((address_space(3))) unsigned int*)lds, 16, 0, 0);
}

// bijective chunked XCD swizzle (m204)
__device__ __forceinline__ int xcd_swz(int o, int nwg) {
  int q = nwg >> 3, r8 = nwg & 7;
  int xcd = o & 7, pos = o >> 3;
  return (xcd < r8) ? xcd * (q + 1) + pos : r8 * (q + 1) + (xcd - r8) * q + pos;
}

// ---------------------------------------------------------------------------
__global__ void rope_tables_k(float* __restrict__ cosT, float* __restrict__ sinT) {
  int t = blockIdx.x;
  int i = threadIdx.x;      // 0..63
  double inv = pow(1000000.0, -(double)i / 64.0);
  double ang = (double)t * inv;
  cosT[t * 64 + i] = (float)cos(ang);
  sinT[t * 64 + i] = (float)sin(ang);
}

// Fused embed gather + first-layer RMSNorm: xf row + hb bf16 row in one pass
__global__ __launch_bounds__(256) void embed_rms_k(const int* __restrict__ ids,
                                                   const float* __restrict__ emb,
                                                   const float* __restrict__ g,
                                                   float* __restrict__ x,
                                                   unsigned short* __restrict__ y) {
  int t = blockIdx.x;
  int id = ids[t];
  const float* src = emb + (size_t)id * Dm;
  float vals[8];
  float s = 0.f;
#pragma unroll
  for (int i = 0; i < 8; ++i) {
    float vv = src[threadIdx.x + i * 256];
    vals[i] = vv;
    s += vv * vv;
  }
#pragma unroll
  for (int off = 32; off; off >>= 1) s += __shfl_xor(s, off);
  __shared__ float red[4];
  if ((threadIdx.x & 63) == 0) red[threadIdx.x >> 6] = s;
  __syncthreads();
  s = (red[0] + red[1]) + (red[2] + red[3]);
  float r = rsqrtf(s * (1.f / Dm) + 1e-6f);
  float* xr = x + (size_t)t * Dm;
  unsigned short* yr = y + (size_t)t * Dm;
#pragma unroll
  for (int i = 0; i < 8; ++i) {
    int d = threadIdx.x + i * 256;
    xr[d] = vals[i];
    yr[d] = f2b(vals[i] * r * g[d]);
  }
}

// fp32 -> bf16 flat convert, 2048 elems per block
__global__ __launch_bounds__(256) void cvt_flat_k(const float* __restrict__ src,
                                                  unsigned short* __restrict__ dst) {
  size_t i = ((size_t)blockIdx.x * 256 + threadIdx.x) * 8;
  f32x4 a = *(const f32x4*)(src + i);
  f32x4 b = *(const f32x4*)(src + i + 4);
  u16x8 o;
  o[0] = f2b(a.x); o[1] = f2b(a.y); o[2] = f2b(a.z); o[3] = f2b(a.w);
  o[4] = f2b(b.x); o[5] = f2b(b.y); o[6] = f2b(b.z); o[7] = f2b(b.w);
  *(u16x8*)(dst + i) = o;
}

__global__ __launch_bounds__(256) void rmsnorm_k(const float* __restrict__ x,
                                                 const float* __restrict__ g,
                                                 unsigned short* __restrict__ y) {
  int t = blockIdx.x;
  const float* xr = x + (size_t)t * Dm;
  float vals[8];
  float s = 0.f;
#pragma unroll
  for (int i = 0; i < 8; ++i) {
    float vv = xr[threadIdx.x + i * 256];
    vals[i] = vv;
    s += vv * vv;
  }
#pragma unroll
  for (int off = 32; off; off >>= 1) s += __shfl_xor(s, off);
  __shared__ float red[4];
  if ((threadIdx.x & 63) == 0) red[threadIdx.x >> 6] = s;
  __syncthreads();
  s = (red[0] + red[1]) + (red[2] + red[3]);
  float r = rsqrtf(s * (1.f / Dm) + 1e-6f);
  unsigned short* yr = y + (size_t)t * Dm;
#pragma unroll
  for (int i = 0; i < 8; ++i) {
    int d = threadIdx.x + i * 256;
    yr[d] = f2b(vals[i] * r * g[d]);
  }
}

__global__ __launch_bounds__(256) void qknorm_rope_k(unsigned short* __restrict__ q,
                                                     const float* __restrict__ nrm,
                                                     const float* __restrict__ cosT,
                                                     const float* __restrict__ sinT,
                                                     int nheads) {
  int gw = (int)((blockIdx.x * blockDim.x + threadIdx.x) >> 6);
  int lane = threadIdx.x & 63;
  int t = gw / nheads, h = gw % nheads;
  unsigned short* row = q + ((size_t)t * nheads + h) * HDm;
  float x1 = b2f(row[lane]);
  float x2 = b2f(row[lane + 64]);
  float s = x1 * x1 + x2 * x2;
#pragma unroll
  for (int off = 32; off; off >>= 1) s += __shfl_xor(s, off);
  float r = rsqrtf(s * (1.f / HDm) + 1e-6f);
  float y1 = x1 * r * nrm[lane];
  float y2 = x2 * r * nrm[lane + 64];
  float c = cosT[t * 64 + lane];
  float sn = sinT[t * 64 + lane];
  row[lane]      = f2b(y1 * c - y2 * sn);
  row[lane + 64] = f2b(y2 * c + y1 * sn);
}

// Weight convert+transpose: W fp32 [K][N] -> Wt bf16 [N][K]
__global__ __launch_bounds__(256) void cvtT_k(const float* __restrict__ W,
                                              unsigned short* __restrict__ Wt,
                                              int K, int N) {
  __shared__ __align__(16) unsigned short tile[64][68];
  const int n0 = blockIdx.x * 64, k0 = blockIdx.y * 64;
  const int tid = threadIdx.x;
#pragma unroll
  for (int i = 0; i < 4; ++i) {
    int e = tid + i * 256;
    int r = e >> 4, c4 = (e & 15) * 4;
    f32x4 v = *(const f32x4*)(W + (size_t)(k0 + r) * N + n0 + c4);
    tile[r][c4 + 0] = f2b(v.x);
    tile[r][c4 + 1] = f2b(v.y);
    tile[r][c4 + 2] = f2b(v.z);
    tile[r][c4 + 3] = f2b(v.w);
  }
  __syncthreads();
#pragma unroll
  for (int i = 0; i < 2; ++i) {
    int e = tid + i * 256;
    int rr = e >> 3, cc = (e & 7) * 8;
    u16x8 o;
#pragma unroll
    for (int j = 0; j < 8; ++j) o[j] = tile[cc + j][rr];
    *(u16x8*)(Wt + (size_t)(n0 + rr) * K + k0 + cc) = o;
  }
}

// ---------------------------------------------------------------------------
// 2-phase 128^2 GEMM (round-12 proven; ld = row stride >= K)
template <int EPI, bool OUTF32>
__global__ __launch_bounds__(256) void gemm2p_k(const unsigned short* __restrict__ A,
                                                const unsigned short* __restrict__ B,
                                                void* __restrict__ C,
                                                void* __restrict__ C2,
                                                void* __restrict__ C3,
                                                int N, int K, int ld, int cOff) {
  __shared__ __align__(16) unsigned short lds[2][2][128 * 64];   // 64 KiB
  const int tid = threadIdx.x;
  const int nwg = gridDim.x * gridDim.y;
  const int nid = xcd_swz(blockIdx.x + gridDim.x * blockIdx.y, nwg);
  const int bm = nid % gridDim.x, bn = nid / gridDim.x;
  const int w = tid >> 6, lane = tid & 63;
  const int wm = (w >> 1) * 64, wn = (w & 1) * 64;
  const int lr = lane & 15, hi = lane >> 4;
  const int rowA0 = bm * 128, colB0 = bn * 128;
  const int nk = K >> 6;

  const int srow = lane >> 3;            // row within 8-row chunk
  const int ulog = (lane & 7) ^ srow;    // pre-swizzled logical k-unit
  const unsigned short* gA = A + (size_t)(rowA0 + w * 32 + srow) * ld + ulog * 8;
  const unsigned short* gB = B + (size_t)(colB0 + w * 32 + srow) * ld + ulog * 8;

  int uu[2];
  uu[0] = ((0 + hi) ^ (lr & 7)) * 8;
  uu[1] = ((4 + hi) ^ (lr & 7)) * 8;

  f32x4 acc[4][4] = {};

  auto stage8 = [&](int buf, int k0) {
    unsigned short* lA = &lds[buf][0][(w * 32) * 64];
    unsigned short* lB = &lds[buf][1][(w * 32) * 64];
#pragma unroll
    for (int i = 0; i < 4; ++i) {
      gload16(gA + (size_t)(i * 8) * ld + k0, lA + i * 8 * 64);
      gload16(gB + (size_t)(i * 8) * ld + k0, lB + i * 8 * 64);
    }
  };

  stage8(0, 0);
  asm volatile("s_waitcnt vmcnt(0)" ::: "memory");
  __builtin_amdgcn_s_barrier();

  for (int kt = 0; kt < nk; ++kt) {
    const int cur = kt & 1;
    if (kt + 1 < nk) stage8(cur ^ 1, (kt + 1) << 6);   // issue early

    const unsigned short* Ac = &lds[cur][0][0];
    const unsigned short* Bc = &lds[cur][1][0];
    bf16x8 av[4][2], bv[4][2];
#pragma unroll
    for (int m = 0; m < 4; ++m) {
      int rb = (wm + m * 16 + lr) * 64;
#pragma unroll
      for (int ks = 0; ks < 2; ++ks)
        av[m][ks] = *(const bf16x8*)&Ac[rb + uu[ks]];
    }
#pragma unroll
    for (int n = 0; n < 4; ++n) {
      int rb = (wn + n * 16 + lr) * 64;
#pragma unroll
      for (int ks = 0; ks < 2; ++ks)
        bv[n][ks] = *(const bf16x8*)&Bc[rb + uu[ks]];
    }
    __builtin_amdgcn_s_setprio(1);
#pragma unroll
    for (int m = 0; m < 4; ++m)
#pragma unroll
      for (int n = 0; n < 4; ++n)
#pragma unroll
        for (int ks = 0; ks < 2; ++ks)
          acc[m][n] = mfma16x16x32(av[m][ks], bv[n][ks], acc[m][n]);
    __builtin_amdgcn_s_setprio(0);

    asm volatile("s_waitcnt vmcnt(0) lgkmcnt(0)" ::: "memory");
    __builtin_amdgcn_sched_barrier(0);
    __builtin_amdgcn_s_barrier();
  }

  const int r0 = rowA0 + wm + hi * 4;
  const int c0 = wn + lr;
#pragma unroll
  for (int m = 0; m < 4; ++m)
#pragma unroll
    for (int n = 0; n < 4; ++n) {
      const int cc = colB0 + c0 + n * 16;
#pragma unroll
      for (int j = 0; j < 4; ++j) {
        int r = r0 + m * 16 + j;
        if (EPI == 0) {
          size_t idx = (size_t)r * N + cOff + cc;
          if (OUTF32) ((float*)C)[idx] = acc[m][n][j];
          else        ((unsigned short*)C)[idx] = f2b(acc[m][n][j]);
        } else if (EPI == 1) {
          ((float*)C)[(size_t)r * N + cc] += acc[m][n][j];
        } else if (EPI == 2) {
          unsigned short* Cb = (unsigned short*)C;
          size_t idx = (size_t)r * N + cc;
          float gg = b2f(Cb[idx]);
          gg = gg / (1.f + __expf(-gg));
          Cb[idx] = f2b(gg * acc[m][n][j]);
        } else {  // EPI==3: QKV split-store
          unsigned short v = f2b(acc[m][n][j]);
          if (cc < 2048)      ((unsigned short*)C )[(size_t)r * 2048 + cc] = v;
          else if (cc < 3072) ((unsigned short*)C2)[(size_t)r * 1024 + (cc - 2048)] = v;
          else                ((unsigned short*)C3)[(size_t)r * 1024 + (cc - 3072)] = v;
        }
      }
    }
}

// ---------------------------------------------------------------------------
// 256^2 8-phase GEMM (round-13 proven, unchanged)
#define LDA256(MH)                                                             \
  _Pragma("unroll") for (int m_ = 0; m_ < 4; ++m_)                             \
  _Pragma("unroll") for (int ks_ = 0; ks_ < 2; ++ks_)                          \
    av[m_][ks_] = *(const bf16x8*)&Ac[aBase + (MH) * 4096 + m_ * 1024 + uu[ks_]];
#define LDB256(NH)                                                             \
  _Pragma("unroll") for (int n_ = 0; n_ < 2; ++n_)                             \
  _Pragma("unroll") for (int ks_ = 0; ks_ < 2; ++ks_)                          \
    bv[n_][ks_] = *(const bf16x8*)&Bc[bBase + (NH) * 2048 + n_ * 1024 + uu[ks_]];
#define MMA256(MH, NH)                                                         \
  __builtin_amdgcn_s_setprio(1);                                               \
  _Pragma("unroll") for (int m_ = 0; m_ < 4; ++m_)                             \
  _Pragma("unroll") for (int n_ = 0; n_ < 2; ++n_)                             \
  _Pragma("unroll") for (int ks_ = 0; ks_ < 2; ++ks_)                          \
    acc[(MH) * 4 + m_][(NH) * 2 + n_] = mfma16x16x32(                          \
        av[m_][ks_], bv[n_][ks_], acc[(MH) * 4 + m_][(NH) * 2 + n_]);          \
  __builtin_amdgcn_s_setprio(0);
#define SYNCV                                                                  \
  asm volatile("s_waitcnt vmcnt(4)" ::: "memory");                             \
  __builtin_amdgcn_s_barrier();                                                \
  asm volatile("s_waitcnt lgkmcnt(0)" ::: "memory");                           \
  __builtin_amdgcn_sched_barrier(0);
#define SYNCNV                                                                 \
  __builtin_amdgcn_s_barrier();                                                \
  asm volatile("s_waitcnt lgkmcnt(0)" ::: "memory");                           \
  __builtin_amdgcn_sched_barrier(0);
#define ENDPH __builtin_amdgcn_s_barrier();

template <int EPI, bool OUTF32>
__global__ __launch_bounds__(512) void gemm256_k(const unsigned short* __restrict__ A,
                                                 const unsigned short* __restrict__ B,
                                                 void* __restrict__ C,
                                                 void* __restrict__ C2,
                                                 void* __restrict__ C3,
                                                 int N, int K, int cOff) {
  __shared__ __align__(16) unsigned short lds[2][2][256 * 64];   // 128 KiB
  const int tid = threadIdx.x;
  const int nwg = gridDim.x * gridDim.y;
  const int nid = xcd_swz(blockIdx.x + gridDim.x * blockIdx.y, nwg);
  const int bm = nid % gridDim.x, bn = nid / gridDim.x;
  const int w = tid >> 6, lane = tid & 63;
  const int wr = w >> 2, wc = w & 3;
  const int lr = lane & 15, hi = lane >> 4;
  const int rowA0 = bm * 256, colB0 = bn * 256;
  const int nk = K >> 6;

  const int srow = lane >> 3;
  const int ulog = (lane & 7) ^ srow;
  const int eaR = (w < 4) ? w * 16 : 128 + (w - 4) * 16;
  const int laR = eaR + 64;
  const int ebR = (w >> 1) * 64 + (w & 1) * 16;
  const int lbR = ebR + 32;
  const unsigned short* gAt = A + (size_t)rowA0 * K + ulog * 8;
  const unsigned short* gBt = B + (size_t)colB0 * K + ulog * 8;

  int uu[2];
  uu[0] = ((0 + hi) ^ (lr & 7)) * 8;
  uu[1] = ((4 + hi) ^ (lr & 7)) * 8;
  const int aBase = (wr * 128 + lr) * 64;
  const int bBase = (wc * 64 + lr) * 64;

  f32x4 acc[8][4] = {};
  bf16x8 av[4][2], bv[2][2];

  auto stage2 = [&](const unsigned short* g, int rbase, unsigned short* l, int k0) {
    gload16(g + (size_t)(rbase + srow) * K + k0, l + rbase * 64);
    gload16(g + (size_t)(rbase + 8 + srow) * K + k0, l + (rbase + 8) * 64);
  };

  stage2(gAt, eaR, &lds[0][0][0], 0);
  stage2(gBt, ebR, &lds[0][1][0], 0);
  stage2(gBt, lbR, &lds[0][1][0], 0);
  stage2(gAt, laR, &lds[0][0][0], 0);
  asm volatile("s_waitcnt vmcnt(0)" ::: "memory");
  __builtin_amdgcn_s_barrier();

  for (int kt = 0; kt < nk; ++kt) {
    unsigned short* Ac = &lds[kt & 1][0][0];
    unsigned short* Bc = &lds[kt & 1][1][0];
    unsigned short* An = &lds[(kt + 1) & 1][0][0];
    unsigned short* Bn = &lds[(kt + 1) & 1][1][0];
    const int k0n = (kt + 1) << 6;
    const bool more = (kt + 1) < nk;

    LDA256(0) LDB256(0)
    if (more) stage2(gAt, eaR, An, k0n);
    SYNCV MMA256(0, 0) ENDPH
    LDB256(1)
    if (more) stage2(gBt, ebR, Bn, k0n);
    SYNCV MMA256(0, 1) ENDPH
    LDA256(1)
    if (more) stage2(gBt, lbR, Bn, k0n);
    SYNCNV MMA256(1, 1) ENDPH
    LDB256(0)
    if (more) stage2(gAt, laR, An, k0n);
    SYNCV MMA256(1, 0) ENDPH
  }

  const int r0 = rowA0 + wr * 128 + hi * 4;
  const int c0 = colB0 + wc * 64 + lr;
#pragma unroll
  for (int mi = 0; mi < 8; ++mi)
#pragma unroll
    for (int n = 0; n < 4; ++n) {
      const int cc = c0 + n * 16;
#pragma unroll
      for (int j = 0; j < 4; ++j) {
        int r = r0 + mi * 16 + j;
        if (EPI == 0) {
          size_t idx = (size_t)r * N + cOff + cc;
          if (OUTF32) ((float*)C)[idx] = acc[mi][n][j];
          else        ((unsigned short*)C)[idx] = f2b(acc[mi][n][j]);
        } else if (EPI == 2) {
          unsigned short* Cb = (unsigned short*)C;
          size_t idx = (size_t)r * N + cc;
          float gg = b2f(Cb[idx]);
          gg = gg / (1.f + __expf(-gg));
          Cb[idx] = f2b(gg * acc[mi][n][j]);
        } else {  // EPI==3: QKV split-store
          unsigned short v = f2b(acc[mi][n][j]);
          if (cc < 2048)      ((unsigned short*)C )[(size_t)r * 2048 + cc] = v;
          else if (cc < 3072) ((unsigned short*)C2)[(size_t)r * 1024 + (cc - 2048)] = v;
          else                ((unsigned short*)C3)[(size_t)r * 1024 + (cc - 3072)] = v;
        }
      }
    }
}

// ---------------------------------------------------------------------------
// MFMA flash attention v5 (round-15 proven, unchanged)
__global__ __launch_bounds__(256) void attn_k(const unsigned short* __restrict__ qg,
                                              const unsigned short* __restrict__ kg,
                                              const unsigned short* __restrict__ vg,
                                              unsigned short* __restrict__ og) {
  __shared__ __align__(16) unsigned short Ks[64 * 128];
  __shared__ __align__(16) unsigned short Vt[128 * 72];
  __shared__ __align__(16) unsigned short Pl[4 * 16 * 72];
  const int tid = threadIdx.x;
  const int nid = xcd_swz(blockIdx.x + (blockIdx.y << 5), 512);
  const int u = nid & 63;
  const int h = ((nid >> 6) << 1) | (u >> 5);
  const int qt = (u < 32) ? u : 63 - u;
  const int w = tid >> 6, lane = tid & 63;
  const int lr = lane & 15, hi = lane >> 4;
  const int kvh = h >> 1;

  size_t goff[4]; unsigned kdst[4]; int vr[4], vc[4];
#pragma unroll
  for (int i = 0; i < 4; ++i) {
    int e = tid + i * 256;
    int r = e >> 4, c = (e & 15) * 8;
    goff[i] = ((size_t)r * KVm + kvh) * HDm + c;
    kdst[i] = (unsigned)((r * 256 + c * 2) ^ ((r & 7) << 4));
    vr[i] = r; vc[i] = c;
  }

  const int t0 = qt * 64;
  const int ntk = qt + 1;

  bf16x8 qa[4];
  {
    const unsigned short* qrow = qg + ((size_t)(t0 + w * 16 + lr) * Hm + h) * HDm;
#pragma unroll
    for (int ks = 0; ks < 4; ++ks)
      qa[ks] = __builtin_bit_cast(bf16x8, *(const u16x8*)(qrow + ks * 32 + hi * 8));
  }

  f32x4 oa[8] = {};
  float mj[4], lj[4];
#pragma unroll
  for (int j = 0; j < 4; ++j) { mj[j] = -3.0e38f; lj[j] = 0.f; }

  u16x8 kk[4], vv[4];
#pragma unroll
  for (int i = 0; i < 4; ++i) {
    kk[i] = *(const u16x8*)(kg + goff[i]);
    vv[i] = *(const u16x8*)(vg + goff[i]);
  }

  for (int t = 0; t < ntk; ++t) {
    __syncthreads();
#pragma unroll
    for (int i = 0; i < 4; ++i) {
      *(u16x8*)((char*)Ks + kdst[i]) = kk[i];
#pragma unroll
      for (int j = 0; j < 8; ++j) {
        int d = vc[i] + j;
        Vt[d * 72 + (vr[i] ^ (((d >> 3) & 7) << 3))] = vv[i][j];
      }
    }
    if (t + 1 < ntk) {
      size_t add = (size_t)(t + 1) * 64 * KVm * HDm;
#pragma unroll
      for (int i = 0; i < 4; ++i) {
        kk[i] = *(const u16x8*)(kg + goff[i] + add);
        vv[i] = *(const u16x8*)(vg + goff[i] + add);
      }
    }
    __syncthreads();

    const int s0 = t * 64;
    f32x4 s[4] = {};
#pragma unroll
    for (int ks = 0; ks < 4; ++ks)
#pragma unroll
      for (int nt = 0; nt < 4; ++nt) {
        int krow = nt * 16 + lr;
        int kbyte = (krow * 256 + (ks * 32 + hi * 8) * 2) ^ ((krow & 7) << 4);
        bf16x8 kf = __builtin_bit_cast(bf16x8, *(const u16x8*)((char*)Ks + kbyte));
        s[nt] = mfma16x16x32(qa[ks], kf, s[nt]);
      }

    float p[4][4];
    const bool maskt = (t == ntk - 1);
#pragma unroll
    for (int nt = 0; nt < 4; ++nt)
#pragma unroll
      for (int j = 0; j < 4; ++j) {
        float val = s[nt][j] * 0.08838834764831845f;
        if (maskt && (s0 + nt * 16 + lr) > (t0 + w * 16 + hi * 4 + j)) val = -1e30f;
        p[nt][j] = val;
      }

#pragma unroll
    for (int j = 0; j < 4; ++j) {
      float mx = fmaxf(fmaxf(p[0][j], p[1][j]), fmaxf(p[2][j], p[3][j]));
#pragma unroll
      for (int msk = 1; msk < 16; msk <<= 1) mx = fmaxf(mx, __shfl_xor(mx, msk));
      float mnew = fmaxf(mj[j], mx);
      float alpha = __expf(mj[j] - mnew);
      mj[j] = mnew;
      float sum = 0.f;
#pragma unroll
      for (int nt = 0; nt < 4; ++nt) {
        float e = __expf(p[nt][j] - mnew);
        p[nt][j] = e;
        sum += e;
      }
#pragma unroll
      for (int msk = 1; msk < 16; msk <<= 1) sum += __shfl_xor(sum, msk);
      lj[j] = lj[j] * alpha + sum;
#pragma unroll
      for (int nt2 = 0; nt2 < 8; ++nt2) oa[nt2][j] *= alpha;
    }

#pragma unroll
    for (int nt = 0; nt < 4; ++nt)
#pragma unroll
      for (int j = 0; j < 4; ++j)
        Pl[(w * 16 + hi * 4 + j) * 72 + nt * 16 + lr] = f2b(p[nt][j]);
    __builtin_amdgcn_sched_barrier(0);

    bf16x8 pa[2];
#pragma unroll
    for (int ks2 = 0; ks2 < 2; ++ks2)
      pa[ks2] = __builtin_bit_cast(bf16x8,
                 *(const u16x8*)&Pl[(w * 16 + lr) * 72 + ks2 * 32 + hi * 8]);
#pragma unroll
    for (int nt2 = 0; nt2 < 8; ++nt2)
#pragma unroll
      for (int ks2 = 0; ks2 < 2; ++ks2) {
        int d = nt2 * 16 + lr;
        int kv = ks2 * 32 + hi * 8;
        bf16x8 vf = __builtin_bit_cast(bf16x8,
                     *(const u16x8*)&Vt[d * 72 + (kv ^ (((d >> 3) & 7) << 3))]);
        oa[nt2] = mfma16x16x32(pa[ks2], vf, oa[nt2]);
      }
  }

#pragma unroll
  for (int nt2 = 0; nt2 < 8; ++nt2)
#pragma unroll
    for (int j = 0; j < 4; ++j) {
      int row = t0 + w * 16 + hi * 4 + j;
      int d = nt2 * 16 + lr;
      og[((size_t)row * Hm + h) * HDm + d] = f2b(oa[nt2][j] / lj[j]);
    }
}

// ---------------------------------------------------------------------------
extern "C" void kernel_launch(void* const* d_in, const int* in_sizes, int n_in,
                              void* d_out, int out_size, void* d_ws, size_t ws_size,
                              hipStream_t stream) {
  (void)in_sizes; (void)n_in; (void)out_size; (void)ws_size;
  const int*   ids = (const int*)d_in[0];
  const float* emb = (const float*)d_in[1];
  const float* Wq  = (const float*)d_in[2];
  const float* Wk  = (const float*)d_in[3];
  const float* Wv  = (const float*)d_in[4];
  const float* Wo  = (const float*)d_in[5];
  const float* qn  = (const float*)d_in[6];
  const float* kn  = (const float*)d_in[7];
  const float* W1  = (const float*)d_in[8];
  const float* W2  = (const float*)d_in[9];
  const float* W3  = (const float*)d_in[10];
  const float* ln1 = (const float*)d_in[11];
  const float* ln2 = (const float*)d_in[12];
  const float* lnf = (const float*)d_in[13];

  char* p = (char*)d_ws;
  float* xf          = (float*)p;          p += (size_t)Tm * Dm * 4;
  unsigned short* hb = (unsigned short*)p; p += (size_t)Tm * Dm * 2;
  float* cosT        = (float*)p;          p += (size_t)Tm * 64 * 4;
  float* sinT        = (float*)p;          p += (size_t)Tm * 64 * 4;
  unsigned short* qb = (unsigned short*)p; p += (size_t)Tm * Hm * HDm * 2;
  unsigned short* kb = (unsigned short*)p; p += (size_t)Tm * KVm * HDm * 2;
  unsigned short* vb = (unsigned short*)p; p += (size_t)Tm * KVm * HDm * 2;
  unsigned short* ob = (unsigned short*)p; p += (size_t)Tm * Hm * HDm * 2;
  unsigned short* wt = (unsigned short*)p; p += (size_t)Dm * FFm * 2;
  unsigned short* g1 = qb;  // FFN alias: qb..ob span == T*FF*2 exactly

  rope_tables_k<<<Tm, 64, 0, stream>>>(cosT, sinT);
  // fused embed + layer-0 rmsnorm (writes xf AND hb)
  embed_rms_k<<<Tm, 256, 0, stream>>>(ids, emb, ln1, xf, hb);

  for (int l = 0; l < 2; ++l) {
    const float* Wq_l = Wq + (size_t)l * Dm * (Hm * HDm);
    const float* Wk_l = Wk + (size_t)l * Dm * (KVm * HDm);
    const float* Wv_l = Wv + (size_t)l * Dm * (KVm * HDm);
    const float* Wo_l = Wo + (size_t)l * (Hm * HDm) * Dm;
    const float* W1_l = W1 + (size_t)l * Dm * FFm;
    const float* W2_l = W2 + (size_t)l * Dm * FFm;
    const float* W3_l = W3 + (size_t)l * FFm * Dm;

    if (l > 0)
      rmsnorm_k<<<Tm, 256, 0, stream>>>(xf, ln1 + (size_t)l * Dm, hb);

    cvtT_k<<<dim3((Hm * HDm) / 64, Dm / 64), 256, 0, stream>>>(Wq_l, wt, Dm, Hm * HDm);
    cvtT_k<<<dim3((KVm * HDm) / 64, Dm / 64), 256, 0, stream>>>(
        Wk_l, wt + (size_t)2048 * Dm, Dm, KVm * HDm);
    cvtT_k<<<dim3((KVm * HDm) / 64, Dm / 64), 256, 0, stream>>>(
        Wv_l, wt + (size_t)3072 * Dm, Dm, KVm * HDm);
    gemm2p_k<3, false><<<dim3(Tm / 128, QKVN / 128), 256, 0, stream>>>(
        hb, wt, qb, kb, vb, QKVN, Dm, Dm, 0);

    qknorm_rope_k<<<(Tm * Hm) / 4, 256, 0, stream>>>(qb, qn + (size_t)l * HDm, cosT, sinT, Hm);
    qknorm_rope_k<<<(Tm * KVm) / 4, 256, 0, stream>>>(kb, kn + (size_t)l * HDm, cosT, sinT, KVm);

    attn_k<<<dim3(32, 16), 256, 0, stream>>>(qb, kb, vb, ob);

    cvtT_k<<<dim3(Dm / 64, (Hm * HDm) / 64), 256, 0, stream>>>(Wo_l, wt, Hm * HDm, Dm);
    gemm2p_k<1, false><<<dim3(Tm / 128, Dm / 128), 256, 0, stream>>>(
        ob, wt, xf, nullptr, nullptr, Dm, Hm * HDm, Hm * HDm, 0);

    rmsnorm_k<<<Tm, 256, 0, stream>>>(xf, ln2 + (size_t)l * Dm, hb);

    cvtT_k<<<dim3(FFm / 64, Dm / 64), 256, 0, stream>>>(W1_l, wt, Dm, FFm);
    gemm256_k<0, false><<<dim3(Tm / 256, FFm / 256), 512, 0, stream>>>(
        hb, wt, g1, nullptr, nullptr, FFm, Dm, 0);
    cvtT_k<<<dim3(FFm / 64, Dm / 64), 256, 0, stream>>>(W2_l, wt, Dm, FFm);
    gemm256_k<2, false><<<dim3(Tm / 256, FFm / 256), 512, 0, stream>>>(
        hb, wt, g1, nullptr, nullptr, FFm, Dm, 0);
    cvtT_k<<<dim3(Dm / 64, FFm / 64), 256, 0, stream>>>(W3_l, wt, FFm, Dm);
    gemm2p_k<1, false><<<dim3(Tm / 128, Dm / 128), 256, 0, stream>>>(
        g1, wt, xf, nullptr, nullptr, Dm, FFm, FFm, 0);
  }

  rmsnorm_k<<<Tm, 256, 0, stream>>>(xf, lnf, hb);

  // logits: 4 bf16 chunks sized for whole grid-rounds (256/256/256/232 blocks)
  unsigned short* embB = qb;
  const int chunks[4] = {8192, 8192, 8192, 7424};
  int off = 0;
  for (int c = 0; c < 4; ++c) {
    const int rows = chunks[c];
    cvt_flat_k<<<rows, 256, 0, stream>>>(emb + (size_t)off * Dm, embB);
    gemm256_k<0, true><<<dim3(Tm / 256, rows / 256), 512, 0, stream>>>(
        hb, embB, d_out, nullptr, nullptr, Vm, Dm, off);
    off += rows;
  }
}

// Round 18
// 1369.484 us; speedup vs baseline: 1.1028x; 1.0078x over previous
//
#include <hip/hip_runtime.h>
#include <math.h>

typedef float f32x4 __attribute__((ext_vector_type(4)));
typedef __bf16 bf16x8 __attribute__((ext_vector_type(8)));
typedef unsigned short u16x8 __attribute__((ext_vector_type(8)));

static constexpr int Dm  = 2048;
static constexpr int Tm  = 2048;
static constexpr int Hm  = 16;
static constexpr int KVm = 8;
static constexpr int HDm = 128;
static constexpr int FFm = 6144;
static constexpr int Vm  = 32000;
static constexpr int QKVN = 4096;

__device__ __forceinline__ float b2f(unsigned short u) {
  unsigned int x = ((unsigned int)u) << 16;
  return __builtin_bit_cast(float, x);
}
__device__ __forceinline__ unsigned short f2b(float f) {
  return __builtin_bit_cast(unsigned short, (__bf16)f);   // v_cvt RTNE
}
__device__ __forceinline__ f32x4 mfma16x16x32(bf16x8 a, bf16x8 b, f32x4 c) {
  return __builtin_amdgcn_mfma_f32_16x16x32_bf16(a, b, c, 0, 0, 0);
}

// async global->LDS, 16B/lane; LDS dest = wave-uniform base + lane*16
__device__ __forceinline__ void gload16(const void* g, void* lds) {
  __builtin_amdgcn_global_load_lds(
      (const __attribute__((address_space(1))) unsigned int*)g,
      (__attribute__((address_space(3))) unsigned int*)lds, 16, 0, 0);
}

// bijective chunked XCD swizzle (m204)
__device__ __forceinline__ int xcd_swz(int o, int nwg) {
  int q = nwg >> 3, r8 = nwg & 7;
  int xcd = o & 7, pos = o >> 3;
  return (xcd < r8) ? xcd * (q + 1) + pos : r8 * (q + 1) + (xcd - r8) * q + pos;
}

// ---------------------------------------------------------------------------
__global__ void rope_tables_k(float* __restrict__ cosT, float* __restrict__ sinT) {
  int t = blockIdx.x;
  int i = threadIdx.x;      // 0..63
  double inv = pow(1000000.0, -(double)i / 64.0);
  double ang = (double)t * inv;
  cosT[t * 64 + i] = (float)cos(ang);
  sinT[t * 64 + i] = (float)sin(ang);
}

// Fused embed gather + first-layer RMSNorm
__global__ __launch_bounds__(256) void embed_rms_k(const int* __restrict__ ids,
                                                   const float* __restrict__ emb,
                                                   const float* __restrict__ g,
                                                   float* __restrict__ x,
                                                   unsigned short* __restrict__ y) {
  int t = blockIdx.x;
  int id = ids[t];
  const float* src = emb + (size_t)id * Dm;
  float vals[8];
  float s = 0.f;
#pragma unroll
  for (int i = 0; i < 8; ++i) {
    float vv = src[threadIdx.x + i * 256];
    vals[i] = vv;
    s += vv * vv;
  }
#pragma unroll
  for (int off = 32; off; off >>= 1) s += __shfl_xor(s, off);
  __shared__ float red[4];
  if ((threadIdx.x & 63) == 0) red[threadIdx.x >> 6] = s;
  __syncthreads();
  s = (red[0] + red[1]) + (red[2] + red[3]);
  float r = rsqrtf(s * (1.f / Dm) + 1e-6f);
  float* xr = x + (size_t)t * Dm;
  unsigned short* yr = y + (size_t)t * Dm;
#pragma unroll
  for (int i = 0; i < 8; ++i) {
    int d = threadIdx.x + i * 256;
    xr[d] = vals[i];
    yr[d] = f2b(vals[i] * r * g[d]);
  }
}

// fp32 -> bf16 flat convert, 2048 elems per block
__global__ __launch_bounds__(256) void cvt_flat_k(const float* __restrict__ src,
                                                  unsigned short* __restrict__ dst) {
  size_t i = ((size_t)blockIdx.x * 256 + threadIdx.x) * 8;
  f32x4 a = *(const f32x4*)(src + i);
  f32x4 b = *(const f32x4*)(src + i + 4);
  u16x8 o;
  o[0] = f2b(a.x); o[1] = f2b(a.y); o[2] = f2b(a.z); o[3] = f2b(a.w);
  o[4] = f2b(b.x); o[5] = f2b(b.y); o[6] = f2b(b.z); o[7] = f2b(b.w);
  *(u16x8*)(dst + i) = o;
}

// xf += p0 + p1 (split-K reduction), 1024 floats per block
__global__ __launch_bounds__(256) void reduce2_k(const float* __restrict__ p0,
                                                 const float* __restrict__ p1,
                                                 float* __restrict__ x) {
  size_t i = ((size_t)blockIdx.x * 256 + threadIdx.x) * 4;
  f32x4 a = *(const f32x4*)(p0 + i);
  f32x4 b = *(const f32x4*)(p1 + i);
  f32x4 c = *(const f32x4*)(x + i);
  c.x += a.x + b.x; c.y += a.y + b.y; c.z += a.z + b.z; c.w += a.w + b.w;
  *(f32x4*)(x + i) = c;
}

__global__ __launch_bounds__(256) void rmsnorm_k(const float* __restrict__ x,
                                                 const float* __restrict__ g,
                                                 unsigned short* __restrict__ y) {
  int t = blockIdx.x;
  const float* xr = x + (size_t)t * Dm;
  float vals[8];
  float s = 0.f;
#pragma unroll
  for (int i = 0; i < 8; ++i) {
    float vv = xr[threadIdx.x + i * 256];
    vals[i] = vv;
    s += vv * vv;
  }
#pragma unroll
  for (int off = 32; off; off >>= 1) s += __shfl_xor(s, off);
  __shared__ float red[4];
  if ((threadIdx.x & 63) == 0) red[threadIdx.x >> 6] = s;
  __syncthreads();
  s = (red[0] + red[1]) + (red[2] + red[3]);
  float r = rsqrtf(s * (1.f / Dm) + 1e-6f);
  unsigned short* yr = y + (size_t)t * Dm;
#pragma unroll
  for (int i = 0; i < 8; ++i) {
    int d = threadIdx.x + i * 256;
    yr[d] = f2b(vals[i] * r * g[d]);
  }
}

__global__ __launch_bounds__(256) void qknorm_rope_k(unsigned short* __restrict__ q,
                                                     const float* __restrict__ nrm,
                                                     const float* __restrict__ cosT,
                                                     const float* __restrict__ sinT,
                                                     int nheads) {
  int gw = (int)((blockIdx.x * blockDim.x + threadIdx.x) >> 6);
  int lane = threadIdx.x & 63;
  int t = gw / nheads, h = gw % nheads;
  unsigned short* row = q + ((size_t)t * nheads + h) * HDm;
  float x1 = b2f(row[lane]);
  float x2 = b2f(row[lane + 64]);
  float s = x1 * x1 + x2 * x2;
#pragma unroll
  for (int off = 32; off; off >>= 1) s += __shfl_xor(s, off);
  float r = rsqrtf(s * (1.f / HDm) + 1e-6f);
  float y1 = x1 * r * nrm[lane];
  float y2 = x2 * r * nrm[lane + 64];
  float c = cosT[t * 64 + lane];
  float sn = sinT[t * 64 + lane];
  row[lane]      = f2b(y1 * c - y2 * sn);
  row[lane + 64] = f2b(y2 * c + y1 * sn);
}

// Weight convert+transpose: W fp32 [K][N] -> Wt bf16 [N][K]
__global__ __launch_bounds__(256) void cvtT_k(const float* __restrict__ W,
                                              unsigned short* __restrict__ Wt,
                                              int K, int N) {
  __shared__ __align__(16) unsigned short tile[64][68];
  const int n0 = blockIdx.x * 64, k0 = blockIdx.y * 64;
  const int tid = threadIdx.x;
#pragma unroll
  for (int i = 0; i < 4; ++i) {
    int e = tid + i * 256;
    int r = e >> 4, c4 = (e & 15) * 4;
    f32x4 v = *(const f32x4*)(W + (size_t)(k0 + r) * N + n0 + c4);
    tile[r][c4 + 0] = f2b(v.x);
    tile[r][c4 + 1] = f2b(v.y);
    tile[r][c4 + 2] = f2b(v.z);
    tile[r][c4 + 3] = f2b(v.w);
  }
  __syncthreads();
#pragma unroll
  for (int i = 0; i < 2; ++i) {
    int e = tid + i * 256;
    int rr = e >> 3, cc = (e & 7) * 8;
    u16x8 o;
#pragma unroll
    for (int j = 0; j < 8; ++j) o[j] = tile[cc + j][rr];
    *(u16x8*)(Wt + (size_t)(n0 + rr) * K + k0 + cc) = o;
  }
}

// ---------------------------------------------------------------------------
// 2-phase 128^2 GEMM (round-16 proven; ld = row stride >= K).
// blockIdx.z selects K-chunk [z*K,(z+1)*K). EPI=5: fp32 partial store.
template <int EPI, bool OUTF32>
__global__ __launch_bounds__(256) void gemm2p_k(const unsigned short* __restrict__ A,
                                                const unsigned short* __restrict__ B,
                                                void* __restrict__ C,
                                                void* __restrict__ C2,
                                                void* __restrict__ C3,
                                                int N, int K, int ld, int cOff) {
  __shared__ __align__(16) unsigned short lds[2][2][128 * 64];   // 64 KiB
  const int tid = threadIdx.x;
  const int nwg = gridDim.x * gridDim.y;
  const int nid = xcd_swz(blockIdx.x + gridDim.x * blockIdx.y, nwg);
  const int bm = nid % gridDim.x, bn = nid / gridDim.x;
  const int w = tid >> 6, lane = tid & 63;
  const int wm = (w >> 1) * 64, wn = (w & 1) * 64;
  const int lr = lane & 15, hi = lane >> 4;
  const int rowA0 = bm * 128, colB0 = bn * 128;
  const int nk = K >> 6;
  const int kz = blockIdx.z * K;

  const int srow = lane >> 3;            // row within 8-row chunk
  const int ulog = (lane & 7) ^ srow;    // pre-swizzled logical k-unit
  const unsigned short* gA = A + (size_t)(rowA0 + w * 32 + srow) * ld + kz + ulog * 8;
  const unsigned short* gB = B + (size_t)(colB0 + w * 32 + srow) * ld + kz + ulog * 8;

  int uu[2];
  uu[0] = ((0 + hi) ^ (lr & 7)) * 8;
  uu[1] = ((4 + hi) ^ (lr & 7)) * 8;

  f32x4 acc[4][4] = {};

  auto stage8 = [&](int buf, int k0) {
    unsigned short* lA = &lds[buf][0][(w * 32) * 64];
    unsigned short* lB = &lds[buf][1][(w * 32) * 64];
#pragma unroll
    for (int i = 0; i < 4; ++i) {
      gload16(gA + (size_t)(i * 8) * ld + k0, lA + i * 8 * 64);
      gload16(gB + (size_t)(i * 8) * ld + k0, lB + i * 8 * 64);
    }
  };

  stage8(0, 0);
  asm volatile("s_waitcnt vmcnt(0)" ::: "memory");
  __builtin_amdgcn_s_barrier();

  for (int kt = 0; kt < nk; ++kt) {
    const int cur = kt & 1;
    if (kt + 1 < nk) stage8(cur ^ 1, (kt + 1) << 6);   // issue early

    const unsigned short* Ac = &lds[cur][0][0];
    const unsigned short* Bc = &lds[cur][1][0];
    bf16x8 av[4][2], bv[4][2];
#pragma unroll
    for (int m = 0; m < 4; ++m) {
      int rb = (wm + m * 16 + lr) * 64;
#pragma unroll
      for (int ks = 0; ks < 2; ++ks)
        av[m][ks] = *(const bf16x8*)&Ac[rb + uu[ks]];
    }
#pragma unroll
    for (int n = 0; n < 4; ++n) {
      int rb = (wn + n * 16 + lr) * 64;
#pragma unroll
      for (int ks = 0; ks < 2; ++ks)
        bv[n][ks] = *(const bf16x8*)&Bc[rb + uu[ks]];
    }
    __builtin_amdgcn_s_setprio(1);
#pragma unroll
    for (int m = 0; m < 4; ++m)
#pragma unroll
      for (int n = 0; n < 4; ++n)
#pragma unroll
        for (int ks = 0; ks < 2; ++ks)
          acc[m][n] = mfma16x16x32(av[m][ks], bv[n][ks], acc[m][n]);
    __builtin_amdgcn_s_setprio(0);

    asm volatile("s_waitcnt vmcnt(0) lgkmcnt(0)" ::: "memory");
    __builtin_amdgcn_sched_barrier(0);
    __builtin_amdgcn_s_barrier();
  }

  const int r0 = rowA0 + wm + hi * 4;
  const int c0 = wn + lr;
#pragma unroll
  for (int m = 0; m < 4; ++m)
#pragma unroll
    for (int n = 0; n < 4; ++n) {
      const int cc = colB0 + c0 + n * 16;
#pragma unroll
      for (int j = 0; j < 4; ++j) {
        int r = r0 + m * 16 + j;
        if (EPI == 0) {
          size_t idx = (size_t)r * N + cOff + cc;
          if (OUTF32) ((float*)C)[idx] = acc[m][n][j];
          else        ((unsigned short*)C)[idx] = f2b(acc[m][n][j]);
        } else if (EPI == 1) {
          ((float*)C)[(size_t)r * N + cc] += acc[m][n][j];
        } else if (EPI == 2) {
          unsigned short* Cb = (unsigned short*)C;
          size_t idx = (size_t)r * N + cc;
          float gg = b2f(Cb[idx]);
          gg = gg / (1.f + __expf(-gg));
          Cb[idx] = f2b(gg * acc[m][n][j]);
        } else if (EPI == 5) {  // split-K fp32 partial store
          float* Cz = (float*)C + (size_t)blockIdx.z * gridDim.x * 128 * N;
          Cz[(size_t)r * N + cc] = acc[m][n][j];
        } else {  // EPI==3: QKV split-store
          unsigned short v = f2b(acc[m][n][j]);
          if (cc < 2048)      ((unsigned short*)C )[(size_t)r * 2048 + cc] = v;
          else if (cc < 3072) ((unsigned short*)C2)[(size_t)r * 1024 + (cc - 2048)] = v;
          else                ((unsigned short*)C3)[(size_t)r * 1024 + (cc - 3072)] = v;
        }
      }
    }
}

// ---------------------------------------------------------------------------
// 256^2 8-phase GEMM (round-16 proven, unchanged)
#define LDA256(MH)                                                             \
  _Pragma("unroll") for (int m_ = 0; m_ < 4; ++m_)                             \
  _Pragma("unroll") for (int ks_ = 0; ks_ < 2; ++ks_)                          \
    av[m_][ks_] = *(const bf16x8*)&Ac[aBase + (MH) * 4096 + m_ * 1024 + uu[ks_]];
#define LDB256(NH)                                                             \
  _Pragma("unroll") for (int n_ = 0; n_ < 2; ++n_)                             \
  _Pragma("unroll") for (int ks_ = 0; ks_ < 2; ++ks_)                          \
    bv[n_][ks_] = *(const bf16x8*)&Bc[bBase + (NH) * 2048 + n_ * 1024 + uu[ks_]];
#define MMA256(MH, NH)                                                         \
  __builtin_amdgcn_s_setprio(1);                                               \
  _Pragma("unroll") for (int m_ = 0; m_ < 4; ++m_)                             \
  _Pragma("unroll") for (int n_ = 0; n_ < 2; ++n_)                             \
  _Pragma("unroll") for (int ks_ = 0; ks_ < 2; ++ks_)                          \
    acc[(MH) * 4 + m_][(NH) * 2 + n_] = mfma16x16x32(                          \
        av[m_][ks_], bv[n_][ks_], acc[(MH) * 4 + m_][(NH) * 2 + n_]);          \
  __builtin_amdgcn_s_setprio(0);
#define SYNCV                                                                  \
  asm volatile("s_waitcnt vmcnt(4)" ::: "memory");                             \
  __builtin_amdgcn_s_barrier();                                                \
  asm volatile("s_waitcnt lgkmcnt(0)" ::: "memory");                           \
  __builtin_amdgcn_sched_barrier(0);
#define SYNCNV                                                                 \
  __builtin_amdgcn_s_barrier();                                                \
  asm volatile("s_waitcnt lgkmcnt(0)" ::: "memory");                           \
  __builtin_amdgcn_sched_barrier(0);
#define ENDPH __builtin_amdgcn_s_barrier();

template <int EPI, bool OUTF32>
__global__ __launch_bounds__(512) void gemm256_k(const unsigned short* __restrict__ A,
                                                 const unsigned short* __restrict__ B,
                                                 void* __restrict__ C,
                                                 void* __restrict__ C2,
                                                 void* __restrict__ C3,
                                                 int N, int K, int cOff) {
  __shared__ __align__(16) unsigned short lds[2][2][256 * 64];   // 128 KiB
  const int tid = threadIdx.x;
  const int nwg = gridDim.x * gridDim.y;
  const int nid = xcd_swz(blockIdx.x + gridDim.x * blockIdx.y, nwg);
  const int bm = nid % gridDim.x, bn = nid / gridDim.x;
  const int w = tid >> 6, lane = tid & 63;
  const int wr = w >> 2, wc = w & 3;
  const int lr = lane & 15, hi = lane >> 4;
  const int rowA0 = bm * 256, colB0 = bn * 256;
  const int nk = K >> 6;

  const int srow = lane >> 3;
  const int ulog = (lane & 7) ^ srow;
  const int eaR = (w < 4) ? w * 16 : 128 + (w - 4) * 16;
  const int laR = eaR + 64;
  const int ebR = (w >> 1) * 64 + (w & 1) * 16;
  const int lbR = ebR + 32;
  const unsigned short* gAt = A + (size_t)rowA0 * K + ulog * 8;
  const unsigned short* gBt = B + (size_t)colB0 * K + ulog * 8;

  int uu[2];
  uu[0] = ((0 + hi) ^ (lr & 7)) * 8;
  uu[1] = ((4 + hi) ^ (lr & 7)) * 8;
  const int aBase = (wr * 128 + lr) * 64;
  const int bBase = (wc * 64 + lr) * 64;

  f32x4 acc[8][4] = {};
  bf16x8 av[4][2], bv[2][2];

  auto stage2 = [&](const unsigned short* g, int rbase, unsigned short* l, int k0) {
    gload16(g + (size_t)(rbase + srow) * K + k0, l + rbase * 64);
    gload16(g + (size_t)(rbase + 8 + srow) * K + k0, l + (rbase + 8) * 64);
  };

  stage2(gAt, eaR, &lds[0][0][0], 0);
  stage2(gBt, ebR, &lds[0][1][0], 0);
  stage2(gBt, lbR, &lds[0][1][0], 0);
  stage2(gAt, laR, &lds[0][0][0], 0);
  asm volatile("s_waitcnt vmcnt(0)" ::: "memory");
  __builtin_amdgcn_s_barrier();

  for (int kt = 0; kt < nk; ++kt) {
    unsigned short* Ac = &lds[kt & 1][0][0];
    unsigned short* Bc = &lds[kt & 1][1][0];
    unsigned short* An = &lds[(kt + 1) & 1][0][0];
    unsigned short* Bn = &lds[(kt + 1) & 1][1][0];
    const int k0n = (kt + 1) << 6;
    const bool more = (kt + 1) < nk;

    LDA256(0) LDB256(0)
    if (more) stage2(gAt, eaR, An, k0n);
    SYNCV MMA256(0, 0) ENDPH
    LDB256(1)
    if (more) stage2(gBt, ebR, Bn, k0n);
    SYNCV MMA256(0, 1) ENDPH
    LDA256(1)
    if (more) stage2(gBt, lbR, Bn, k0n);
    SYNCNV MMA256(1, 1) ENDPH
    LDB256(0)
    if (more) stage2(gAt, laR, An, k0n);
    SYNCV MMA256(1, 0) ENDPH
  }

  const int r0 = rowA0 + wr * 128 + hi * 4;
  const int c0 = colB0 + wc * 64 + lr;
#pragma unroll
  for (int mi = 0; mi < 8; ++mi)
#pragma unroll
    for (int n = 0; n < 4; ++n) {
      const int cc = c0 + n * 16;
#pragma unroll
      for (int j = 0; j < 4; ++j) {
        int r = r0 + mi * 16 + j;
        if (EPI == 0) {
          size_t idx = (size_t)r * N + cOff + cc;
          if (OUTF32) ((float*)C)[idx] = acc[mi][n][j];
          else        ((unsigned short*)C)[idx] = f2b(acc[mi][n][j]);
        } else if (EPI == 2) {
          unsigned short* Cb = (unsigned short*)C;
          size_t idx = (size_t)r * N + cc;
          float gg = b2f(Cb[idx]);
          gg = gg / (1.f + __expf(-gg));
          Cb[idx] = f2b(gg * acc[mi][n][j]);
        } else {  // EPI==3: QKV split-store
          unsigned short v = f2b(acc[mi][n][j]);
          if (cc < 2048)      ((unsigned short*)C )[(size_t)r * 2048 + cc] = v;
          else if (cc < 3072) ((unsigned short*)C2)[(size_t)r * 1024 + (cc - 2048)] = v;
          else                ((unsigned short*)C3)[(size_t)r * 1024 + (cc - 3072)] = v;
        }
      }
    }
}

// ---------------------------------------------------------------------------
// MFMA flash attention v5 (round-15 proven, unchanged)
__global__ __launch_bounds__(256) void attn_k(const unsigned short* __restrict__ qg,
                                              const unsigned short* __restrict__ kg,
                                              const unsigned short* __restrict__ vg,
                                              unsigned short* __restrict__ og) {
  __shared__ __align__(16) unsigned short Ks[64 * 128];
  __shared__ __align__(16) unsigned short Vt[128 * 72];
  __shared__ __align__(16) unsigned short Pl[4 * 16 * 72];
  const int tid = threadIdx.x;
  const int nid = xcd_swz(blockIdx.x + (blockIdx.y << 5), 512);
  const int u = nid & 63;
  const int h = ((nid >> 6) << 1) | (u >> 5);
  const int qt = (u < 32) ? u : 63 - u;
  const int w = tid >> 6, lane = tid & 63;
  const int lr = lane & 15, hi = lane >> 4;
  const int kvh = h >> 1;

  size_t goff[4]; unsigned kdst[4]; int vr[4], vc[4];
#pragma unroll
  for (int i = 0; i < 4; ++i) {
    int e = tid + i * 256;
    int r = e >> 4, c = (e & 15) * 8;
    goff[i] = ((size_t)r * KVm + kvh) * HDm + c;
    kdst[i] = (unsigned)((r * 256 + c * 2) ^ ((r & 7) << 4));
    vr[i] = r; vc[i] = c;
  }

  const int t0 = qt * 64;
  const int ntk = qt + 1;

  bf16x8 qa[4];
  {
    const unsigned short* qrow = qg + ((size_t)(t0 + w * 16 + lr) * Hm + h) * HDm;
#pragma unroll
    for (int ks = 0; ks < 4; ++ks)
      qa[ks] = __builtin_bit_cast(bf16x8, *(const u16x8*)(qrow + ks * 32 + hi * 8));
  }

  f32x4 oa[8] = {};
  float mj[4], lj[4];
#pragma unroll
  for (int j = 0; j < 4; ++j) { mj[j] = -3.0e38f; lj[j] = 0.f; }

  u16x8 kk[4], vv[4];
#pragma unroll
  for (int i = 0; i < 4; ++i) {
    kk[i] = *(const u16x8*)(kg + goff[i]);
    vv[i] = *(const u16x8*)(vg + goff[i]);
  }

  for (int t = 0; t < ntk; ++t) {
    __syncthreads();
#pragma unroll
    for (int i = 0; i < 4; ++i) {
      *(u16x8*)((char*)Ks + kdst[i]) = kk[i];
#pragma unroll
      for (int j = 0; j < 8; ++j) {
        int d = vc[i] + j;
        Vt[d * 72 + (vr[i] ^ (((d >> 3) & 7) << 3))] = vv[i][j];
      }
    }
    if (t + 1 < ntk) {
      size_t add = (size_t)(t + 1) * 64 * KVm * HDm;
#pragma unroll
      for (int i = 0; i < 4; ++i) {
        kk[i] = *(const u16x8*)(kg + goff[i] + add);
        vv[i] = *(const u16x8*)(vg + goff[i] + add);
      }
    }
    __syncthreads();

    const int s0 = t * 64;
    f32x4 s[4] = {};
#pragma unroll
    for (int ks = 0; ks < 4; ++ks)
#pragma unroll
      for (int nt = 0; nt < 4; ++nt) {
        int krow = nt * 16 + lr;
        int kbyte = (krow * 256 + (ks * 32 + hi * 8) * 2) ^ ((krow & 7) << 4);
        bf16x8 kf = __builtin_bit_cast(bf16x8, *(const u16x8*)((char*)Ks + kbyte));
        s[nt] = mfma16x16x32(qa[ks], kf, s[nt]);
      }

    float p[4][4];
    const bool maskt = (t == ntk - 1);
#pragma unroll
    for (int nt = 0; nt < 4; ++nt)
#pragma unroll
      for (int j = 0; j < 4; ++j) {
        float val = s[nt][j] * 0.08838834764831845f;
        if (maskt && (s0 + nt * 16 + lr) > (t0 + w * 16 + hi * 4 + j)) val = -1e30f;
        p[nt][j] = val;
      }

#pragma unroll
    for (int j = 0; j < 4; ++j) {
      float mx = fmaxf(fmaxf(p[0][j], p[1][j]), fmaxf(p[2][j], p[3][j]));
#pragma unroll
      for (int msk = 1; msk < 16; msk <<= 1) mx = fmaxf(mx, __shfl_xor(mx, msk));
      float mnew = fmaxf(mj[j], mx);
      float alpha = __expf(mj[j] - mnew);
      mj[j] = mnew;
      float sum = 0.f;
#pragma unroll
      for (int nt = 0; nt < 4; ++nt) {
        float e = __expf(p[nt][j] - mnew);
        p[nt][j] = e;
        sum += e;
      }
#pragma unroll
      for (int msk = 1; msk < 16; msk <<= 1) sum += __shfl_xor(sum, msk);
      lj[j] = lj[j] * alpha + sum;
#pragma unroll
      for (int nt2 = 0; nt2 < 8; ++nt2) oa[nt2][j] *= alpha;
    }

#pragma unroll
    for (int nt = 0; nt < 4; ++nt)
#pragma unroll
      for (int j = 0; j < 4; ++j)
        Pl[(w * 16 + hi * 4 + j) * 72 + nt * 16 + lr] = f2b(p[nt][j]);
    __builtin_amdgcn_sched_barrier(0);

    bf16x8 pa[2];
#pragma unroll
    for (int ks2 = 0; ks2 < 2; ++ks2)
      pa[ks2] = __builtin_bit_cast(bf16x8,
                 *(const u16x8*)&Pl[(w * 16 + lr) * 72 + ks2 * 32 + hi * 8]);
#pragma unroll
    for (int nt2 = 0; nt2 < 8; ++nt2)
#pragma unroll
      for (int ks2 = 0; ks2 < 2; ++ks2) {
        int d = nt2 * 16 + lr;
        int kv = ks2 * 32 + hi * 8;
        bf16x8 vf = __builtin_bit_cast(bf16x8,
                     *(const u16x8*)&Vt[d * 72 + (kv ^ (((d >> 3) & 7) << 3))]);
        oa[nt2] = mfma16x16x32(pa[ks2], vf, oa[nt2]);
      }
  }

#pragma unroll
  for (int nt2 = 0; nt2 < 8; ++nt2)
#pragma unroll
    for (int j = 0; j < 4; ++j) {
      int row = t0 + w * 16 + hi * 4 + j;
      int d = nt2 * 16 + lr;
      og[((size_t)row * Hm + h) * HDm + d] = f2b(oa[nt2][j] / lj[j]);
    }
}

// ---------------------------------------------------------------------------
extern "C" void kernel_launch(void* const* d_in, const int* in_sizes, int n_in,
                              void* d_out, int out_size, void* d_ws, size_t ws_size,
                              hipStream_t stream) {
  (void)in_sizes; (void)n_in; (void)out_size;
  const int*   ids = (const int*)d_in[0];
  const float* emb = (const float*)d_in[1];
  const float* Wq  = (const float*)d_in[2];
  const float* Wk  = (const float*)d_in[3];
  const float* Wv  = (const float*)d_in[4];
  const float* Wo  = (const float*)d_in[5];
  const float* qn  = (const float*)d_in[6];
  const float* kn  = (const float*)d_in[7];
  const float* W1  = (const float*)d_in[8];
  const float* W2  = (const float*)d_in[9];
  const float* W3  = (const float*)d_in[10];
  const float* ln1 = (const float*)d_in[11];
  const float* ln2 = (const float*)d_in[12];
  const float* lnf = (const float*)d_in[13];

  char* p = (char*)d_ws;
  float* xf          = (float*)p;          p += (size_t)Tm * Dm * 4;
  unsigned short* hb = (unsigned short*)p; p += (size_t)Tm * Dm * 2;
  float* cosT        = (float*)p;          p += (size_t)Tm * 64 * 4;
  float* sinT        = (float*)p;          p += (size_t)Tm * 64 * 4;
  unsigned short* qb = (unsigned short*)p; p += (size_t)Tm * Hm * HDm * 2;
  unsigned short* kb = (unsigned short*)p; p += (size_t)Tm * KVm * HDm * 2;
  unsigned short* vb = (unsigned short*)p; p += (size_t)Tm * KVm * HDm * 2;
  unsigned short* ob = (unsigned short*)p; p += (size_t)Tm * Hm * HDm * 2;
  unsigned short* wt = (unsigned short*)p; p += (size_t)Dm * FFm * 2;
  unsigned short* g1 = qb;  // FFN alias: qb..ob span == T*FF*2 exactly

  // split-K partials (guarded; ws ≈ 1 GB per fill evidence)
  const size_t extOff = (size_t)(p - (char*)d_ws);
  float* pp = (float*)p;
  const bool haveP = ws_size >= extOff + (size_t)2 * Tm * Dm * 4;

  rope_tables_k<<<Tm, 64, 0, stream>>>(cosT, sinT);
  embed_rms_k<<<Tm, 256, 0, stream>>>(ids, emb, ln1, xf, hb);

  for (int l = 0; l < 2; ++l) {
    const float* Wq_l = Wq + (size_t)l * Dm * (Hm * HDm);
    const float* Wk_l = Wk + (size_t)l * Dm * (KVm * HDm);
    const float* Wv_l = Wv + (size_t)l * Dm * (KVm * HDm);
    const float* Wo_l = Wo + (size_t)l * (Hm * HDm) * Dm;
    const float* W1_l = W1 + (size_t)l * Dm * FFm;
    const float* W2_l = W2 + (size_t)l * Dm * FFm;
    const float* W3_l = W3 + (size_t)l * FFm * Dm;

    if (l > 0)
      rmsnorm_k<<<Tm, 256, 0, stream>>>(xf, ln1 + (size_t)l * Dm, hb);

    cvtT_k<<<dim3((Hm * HDm) / 64, Dm / 64), 256, 0, stream>>>(Wq_l, wt, Dm, Hm * HDm);
    cvtT_k<<<dim3((KVm * HDm) / 64, Dm / 64), 256, 0, stream>>>(
        Wk_l, wt + (size_t)2048 * Dm, Dm, KVm * HDm);
    cvtT_k<<<dim3((KVm * HDm) / 64, Dm / 64), 256, 0, stream>>>(
        Wv_l, wt + (size_t)3072 * Dm, Dm, KVm * HDm);
    gemm2p_k<3, false><<<dim3(Tm / 128, QKVN / 128), 256, 0, stream>>>(
        hb, wt, qb, kb, vb, QKVN, Dm, Dm, 0);

    qknorm_rope_k<<<(Tm * Hm) / 4, 256, 0, stream>>>(qb, qn + (size_t)l * HDm, cosT, sinT, Hm);
    qknorm_rope_k<<<(Tm * KVm) / 4, 256, 0, stream>>>(kb, kn + (size_t)l * HDm, cosT, sinT, KVm);

    attn_k<<<dim3(32, 16), 256, 0, stream>>>(qb, kb, vb, ob);

    cvtT_k<<<dim3(Dm / 64, (Hm * HDm) / 64), 256, 0, stream>>>(Wo_l, wt, Hm * HDm, Dm);
    gemm2p_k<1, false><<<dim3(Tm / 128, Dm / 128), 256, 0, stream>>>(
        ob, wt, xf, nullptr, nullptr, Dm, Hm * HDm, Hm * HDm, 0);

    rmsnorm_k<<<Tm, 256, 0, stream>>>(xf, ln2 + (size_t)l * Dm, hb);

    cvtT_k<<<dim3(FFm / 64, Dm / 64), 256, 0, stream>>>(W1_l, wt, Dm, FFm);
    gemm256_k<0, false><<<dim3(Tm / 256, FFm / 256), 512, 0, stream>>>(
        hb, wt, g1, nullptr, nullptr, FFm, Dm, 0);
    cvtT_k<<<dim3(FFm / 64, Dm / 64), 256, 0, stream>>>(W2_l, wt, Dm, FFm);
    gemm256_k<2, false><<<dim3(Tm / 256, FFm / 256), 512, 0, stream>>>(
        hb, wt, g1, nullptr, nullptr, FFm, Dm, 0);
    cvtT_k<<<dim3(Dm / 64, FFm / 64), 256, 0, stream>>>(W3_l, wt, FFm, Dm);
    if (haveP) {
      // split-K=2, fp32 partials (no atomics), then xf += p0 + p1
      gemm2p_k<5, true><<<dim3(Tm / 128, Dm / 128, 2), 256, 0, stream>>>(
          g1, wt, pp, nullptr, nullptr, Dm, FFm / 2, FFm, 0);
      reduce2_k<<<(Tm * Dm) / 1024, 256, 0, stream>>>(
          pp, pp + (size_t)Tm * Dm, xf);
    } else {
      gemm2p_k<1, false><<<dim3(Tm / 128, Dm / 128), 256, 0, stream>>>(
          g1, wt, xf, nullptr, nullptr, Dm, FFm, FFm, 0);
    }
  }

  rmsnorm_k<<<Tm, 256, 0, stream>>>(xf, lnf, hb);

  // logits: r16-proven 4-chunk path (verbatim)
  unsigned short* embB = qb;
  const int chunks[4] = {8192, 8192, 8192, 7424};
  int off = 0;
  for (int c = 0; c < 4; ++c) {
    const int rows = chunks[c];
    cvt_flat_k<<<rows, 256, 0, stream>>>(emb + (size_t)off * Dm, embB);
    gemm256_k<0, true><<<dim3(Tm / 256, rows / 256), 512, 0, stream>>>(
        hb, embB, d_out, nullptr, nullptr, Vm, Dm, off);
    off += rows;
  }
}